// Round 8
// baseline (977.248 us; speedup 1.0000x reference)
//
#include <hip/hip_runtime.h>

#define BATCH 256
#define DIM 512
#define NACT 3
#define NMEM 25000
#define KNB 50
#define H1N 256
#define H2N 128
#define NSTEPS 5
#define KDELTA 0.001f

#define TB 128
#define TN 128
#define BK 64
#define NYT ((NMEM + TN - 1) / TN)   // 196 n-tiles

#define CAP 2048           // candidate buffer cap

typedef __attribute__((ext_vector_type(8))) short short8;
typedef __attribute__((ext_vector_type(4))) float f32x4;

__device__ __forceinline__ unsigned short bf16rn(float f) {
    unsigned u = __float_as_uint(f);
    u += 0x7FFFu + ((u >> 16) & 1u);
    return (unsigned short)(u >> 16);
}
__device__ __forceinline__ float blo(unsigned u) { return __uint_as_float(u << 16); }
__device__ __forceinline__ float bhi(unsigned u) { return __uint_as_float(u & 0xFFFF0000u); }

// ---------- key row norms (one wave per row) ----------
__global__ __launch_bounds__(256)
void knorm_kernel(const float* __restrict__ rows, float* __restrict__ kn, int nrows) {
    int wave = threadIdx.x >> 6, lane = threadIdx.x & 63;
    int r = blockIdx.x * 4 + wave;
    if (r >= nrows) return;
    const float* p = rows + (size_t)r * DIM;
    float4 v0 = *(const float4*)(p + lane * 8);
    float4 v1 = *(const float4*)(p + lane * 8 + 4);
    float s = v0.x*v0.x + v0.y*v0.y + v0.z*v0.z + v0.w*v0.w
            + v1.x*v1.x + v1.y*v1.y + v1.z*v1.z + v1.w*v1.w;
    for (int off = 32; off; off >>= 1) s += __shfl_down(s, off);
    if (lane == 0) kn[r] = s;
}

// ---------- prep x: bf16 copy + qn ----------
__global__ __launch_bounds__(256)
void prep_x_kernel(const float* __restrict__ rows, unsigned short* __restrict__ eb,
                   float* __restrict__ qn, int nrows) {
    int wave = threadIdx.x >> 6, lane = threadIdx.x & 63;
    int r = blockIdx.x * 4 + wave;
    if (r >= nrows) return;
    const float* p = rows + (size_t)r * DIM;
    float4 v0 = *(const float4*)(p + lane * 8);
    float4 v1 = *(const float4*)(p + lane * 8 + 4);
    float f[8] = {v0.x, v0.y, v0.z, v0.w, v1.x, v1.y, v1.z, v1.w};
    short8 hv;
    float s = 0.f;
    #pragma unroll
    for (int i = 0; i < 8; ++i) { hv[i] = (short)bf16rn(f[i]); s += f[i] * f[i]; }
    *(short8*)(eb + (size_t)r * DIM + lane * 8) = hv;
    for (int off = 32; off; off >>= 1) s += __shfl_down(s, off);
    if (lane == 0) qn[r] = s;
}

// ---------- group batch rows by action, all steps in one launch ----------
__global__ __launch_bounds__(256)
void group_all_kernel(const int* __restrict__ actions,
                      int* __restrict__ perm, int* __restrict__ cnt) {
    int step = blockIdx.x;
    __shared__ int lcnt[NACT];
    __shared__ int lperm[NACT * BATCH];
    int tid = threadIdx.x;
    if (tid < NACT) lcnt[tid] = 0;
    __syncthreads();
    int a = actions[tid * NSTEPS + step];
    int pos = atomicAdd(&lcnt[a], 1);
    lperm[a * BATCH + pos] = tid;
    __syncthreads();
    if (tid < NACT) cnt[step * 4 + tid] = lcnt[tid];
    for (int aa = 0; aa < NACT; ++aa) {
        int c = lcnt[aa];
        int f = (c > 0) ? lperm[aa * BATCH] : 0;
        for (int i = c + tid; i < BATCH; i += 256) lperm[aa * BATCH + i] = f;
    }
    __syncthreads();
    for (int i = tid; i < NACT * BATCH; i += 256)
        perm[step * NACT * BATCH + i] = lperm[i];
}

// ---------- approx distance GEMM: bf16 MFMA, f32-K on-the-fly convert, reg prefetch ----------
// also emits per-row partial sums/sumsq for the threshold stats
__global__ __launch_bounds__(256)
void dist_kernel(const unsigned short* __restrict__ eb, const float* __restrict__ keys,
                 const float* __restrict__ kn, const int* __restrict__ perm,
                 const int* __restrict__ cnt, unsigned short* __restrict__ dist,
                 float* __restrict__ psum, float* __restrict__ psq) {
    int a = blockIdx.x >> 1;
    int tb0 = (blockIdx.x & 1) * TB;
    int c = cnt[a];
    if (tb0 >= c) return;
    int n0 = blockIdx.y * TN;

    __shared__ __align__(16) unsigned short Qh[TB][BK];
    __shared__ __align__(16) unsigned short Kh[TN][BK];
    __shared__ int rows[TB];

    int tid = threadIdx.x;
    if (tid < TB) {
        int i = tb0 + tid;
        rows[tid] = perm[a * BATCH + (i < c ? i : 0)];
    }
    __syncthreads();

    int lane = tid & 63, wave = tid >> 6;
    int wm = wave >> 1, wn = wave & 1;

    f32x4 acc[4][4] = {};

    int sr = tid >> 1, sc = (tid & 1) * 32;
    int swz = (sr & 7) * 8;
    int krow = (n0 + sr < NMEM) ? (n0 + sr) : (NMEM - 1);
    const unsigned short* qsrc = eb + (size_t)rows[sr] * DIM + sc;
    const float* ksrc = keys + (size_t)a * NMEM * DIM + (size_t)krow * DIM + sc;

    short8 qv[4];
    float4 kf[8];
    #pragma unroll
    for (int j = 0; j < 4; ++j) qv[j] = *(const short8*)(qsrc + j * 8);
    #pragma unroll
    for (int j = 0; j < 8; ++j) kf[j] = *(const float4*)(ksrc + j * 4);

    for (int d0 = 0; d0 < DIM; d0 += BK) {
        // write staged regs to LDS (swizzled); convert K f32->bf16 here
        #pragma unroll
        for (int j = 0; j < 4; ++j)
            *(short8*)&Qh[sr][(sc + j * 8) ^ swz] = qv[j];
        #pragma unroll
        for (int j = 0; j < 4; ++j) {
            float f[8] = {kf[2*j].x, kf[2*j].y, kf[2*j].z, kf[2*j].w,
                          kf[2*j+1].x, kf[2*j+1].y, kf[2*j+1].z, kf[2*j+1].w};
            short8 hv;
            #pragma unroll
            for (int i = 0; i < 8; ++i) hv[i] = (short)bf16rn(f[i]);
            *(short8*)&Kh[sr][(sc + j * 8) ^ swz] = hv;
        }
        __syncthreads();
        // prefetch next chunk (latency hides under MFMA phase)
        if (d0 + BK < DIM) {
            #pragma unroll
            for (int j = 0; j < 4; ++j) qv[j] = *(const short8*)(qsrc + d0 + BK + j * 8);
            #pragma unroll
            for (int j = 0; j < 8; ++j) kf[j] = *(const float4*)(ksrc + d0 + BK + j * 4);
        }
        #pragma unroll
        for (int kk = 0; kk < BK; kk += 32) {
            int kcol = kk + (lane >> 4) * 8;
            short8 av[4], bv[4];
            #pragma unroll
            for (int mf = 0; mf < 4; ++mf) {
                int m = wm * 64 + mf * 16 + (lane & 15);
                av[mf] = *(const short8*)&Qh[m][kcol ^ ((m & 7) * 8)];
            }
            #pragma unroll
            for (int nf = 0; nf < 4; ++nf) {
                int n = wn * 64 + nf * 16 + (lane & 15);
                bv[nf] = *(const short8*)&Kh[n][kcol ^ ((n & 7) * 8)];
            }
            #pragma unroll
            for (int mf = 0; mf < 4; ++mf)
                #pragma unroll
                for (int nf = 0; nf < 4; ++nf)
                    acc[mf][nf] = __builtin_amdgcn_mfma_f32_16x16x32_bf16(av[mf], bv[nf], acc[mf][nf], 0, 0, 0);
        }
        __syncthreads();
    }

    // ---- epilogue: store bf16 dist + per-row stats partials ----
    // C/D layout: col=lane&15, row=(lane>>4)*4+reg
    int nn[4]; float knv[4]; bool nvalid[4];
    #pragma unroll
    for (int nf = 0; nf < 4; ++nf) {
        nn[nf] = n0 + wn * 64 + nf * 16 + (lane & 15);
        nvalid[nf] = nn[nf] < NMEM;
        knv[nf] = nvalid[nf] ? kn[a * NMEM + nn[nf]] : 0.f;
    }
    int slot = (blockIdx.y * 2 + wn) * BATCH;
    #pragma unroll
    for (int mf = 0; mf < 4; ++mf) {
        #pragma unroll
        for (int r = 0; r < 4; ++r) {
            int m = wm * 64 + mf * 16 + (lane >> 4) * 4 + r;
            int b = rows[m];
            float s = 0.f, q2 = 0.f;
            #pragma unroll
            for (int nf = 0; nf < 4; ++nf) {
                if (nvalid[nf]) {
                    float d = knv[nf] - 2.0f * acc[mf][nf][r];
                    dist[(size_t)b * NMEM + nn[nf]] = bf16rn(d);
                    s += d; q2 += d * d;
                }
            }
            #pragma unroll
            for (int x = 1; x < 16; x <<= 1) { s += __shfl_xor(s, x); q2 += __shfl_xor(q2, x); }
            if ((lane & 15) == 0) { psum[slot + b] = s; psq[slot + b] = q2; }
        }
    }
}

// ---------- threshold from stats partials (one wave per row) ----------
__global__ __launch_bounds__(256)
void thresh_kernel(const float* __restrict__ psum, const float* __restrict__ psq,
                   float* __restrict__ Tb, float* __restrict__ sdb) {
    int wave = threadIdx.x >> 6, lane = threadIdx.x & 63;
    int b = blockIdx.x * 4 + wave;
    float s = 0.f, q = 0.f;
    for (int i = lane; i < NYT * 2; i += 64) {
        s += psum[i * BATCH + b];
        q += psq[i * BATCH + b];
    }
    for (int off = 32; off; off >>= 1) { s += __shfl_down(s, off); q += __shfl_down(q, off); }
    if (lane == 0) {
        float mean = s / (float)NMEM;
        float var = q / (float)NMEM - mean * mean;
        float sd = sqrtf(fmaxf(var, 0.f));
        Tb[b] = mean - 2.45f * sd;
        sdb[b] = sd;
    }
}

// ---------- select: candidate collect (threshold) -> exact f32 refine -> top-50 ----------
__global__ __launch_bounds__(1024)
void select_kernel(const unsigned short* __restrict__ dist, const float* __restrict__ emb,
                   const float* __restrict__ keys, const float* __restrict__ kn,
                   const float* __restrict__ qn, const float* __restrict__ Tb,
                   const float* __restrict__ sdb, const int* __restrict__ actions,
                   int step, int* __restrict__ idx_out, float* __restrict__ w_out) {
    __shared__ float qs[DIM];
    __shared__ unsigned cntS;
    __shared__ int candb[CAP];
    __shared__ float dex[CAP];
    __shared__ float wsel[KNB];
    __shared__ int   isel[KNB];
    __shared__ float wsumS;

    int b = blockIdx.x, tid = threadIdx.x;
    const uint4* d8 = (const uint4*)(dist + (size_t)b * NMEM);   // 8 bf16 per uint4

    if (tid < 128) *(float4*)&qs[tid * 4] = *(const float4*)(emb + (size_t)b * DIM + tid * 4);

    // ---- phase 1: collect all d < T (widen if under 128) ----
    float T = Tb[b], sd = sdb[b];
    for (int it = 0; it < 8; ++it) {
        if (tid == 0) cntS = 0;
        __syncthreads();
        for (int i = tid; i < NMEM / 8; i += 1024) {
            uint4 v = d8[i];
            int n = i * 8;
            float f[8] = {blo(v.x), bhi(v.x), blo(v.y), bhi(v.y),
                          blo(v.z), bhi(v.z), blo(v.w), bhi(v.w)};
            #pragma unroll
            for (int k = 0; k < 8; ++k)
                if (f[k] < T) { unsigned p = atomicAdd(&cntS, 1u); if (p < CAP) candb[p] = n + k; }
        }
        __syncthreads();
        if (cntS >= 128) break;
        T += 0.6f * sd;
        __syncthreads();
    }
    int C = (int)cntS; if (C > CAP) C = CAP;

    // ---- phase 2: exact f32 distances (8 threads/cand, interleaved dims: conflict-free) ----
    int a = actions[b * NSTEPS + step];
    float qnb = qn[b];
    const float* keysA = keys + (size_t)a * NMEM * DIM;
    int cslot = tid >> 3, sub = tid & 7;
    int sweeps = (C + 127) >> 7;
    for (int sw = 0; sw < sweeps; ++sw) {
        int ci = (sw << 7) + cslot;
        float dot = 0.f;
        int n = 0;
        if (ci < C) {
            n = candb[ci];
            const float* kr = keysA + (size_t)n * DIM;
            #pragma unroll
            for (int k = 0; k < 16; ++k) {
                int o = sub * 4 + k * 32;
                float4 kv = *(const float4*)(kr + o);
                dot = fmaf(kv.x, qs[o+0], dot);
                dot = fmaf(kv.y, qs[o+1], dot);
                dot = fmaf(kv.z, qs[o+2], dot);
                dot = fmaf(kv.w, qs[o+3], dot);
            }
        }
        dot += __shfl_xor(dot, 1);
        dot += __shfl_xor(dot, 2);
        dot += __shfl_xor(dot, 4);
        if (ci < C && sub == 0)
            dex[ci] = qnb + kn[a * NMEM + n] - 2.0f * dot;
    }
    __syncthreads();

    // ---- phase 3: exact (d, idx) rank; top-50 ----
    for (int ci = tid; ci < C; ci += 1024) {
        float di = dex[ci]; int ni = candb[ci];
        int rank = 0;
        for (int j = 0; j < C; ++j) {
            float dj = dex[j];
            rank += (dj < di || (dj == di && candb[j] < ni)) ? 1 : 0;
        }
        if (rank < KNB) { wsel[rank] = 1.0f / (di + KDELTA); isel[rank] = ni; }
    }
    __syncthreads();
    if (tid == 0) {
        float ssum = 0.f;
        for (int i = 0; i < KNB; ++i) ssum += wsel[i];
        wsumS = ssum;
    }
    __syncthreads();
    if (tid < KNB) {
        w_out[b * KNB + tid] = wsel[tid] / wsumS;
        idx_out[b * KNB + tid] = isel[tid];
    }
}

// ---------- fused gather + next-qn + bf16 emb + 3-layer MLP ----------
__global__ __launch_bounds__(256)
void gp_kernel(const float* __restrict__ vals, const int* __restrict__ idx,
               const float* __restrict__ w, const int* __restrict__ actions, int step,
               float* __restrict__ emb_out, unsigned short* __restrict__ eb_out,
               float* __restrict__ qn_out,
               const float* __restrict__ w1, const float* __restrict__ b1,
               const float* __restrict__ w2, const float* __restrict__ b2,
               const float* __restrict__ w3, const float* __restrict__ b3,
               float* __restrict__ out) {
    int b = blockIdx.x, tid = threadIdx.x;
    int a = actions[b * NSTEPS + step];
    __shared__ float wl[KNB];
    __shared__ int il[KNB];
    __shared__ float red[256];
    __shared__ float xs[DIM];
    __shared__ float h1[H1N];
    __shared__ float h2[H2N];
    if (tid < KNB) { wl[tid] = w[b * KNB + tid]; il[tid] = idx[b * KNB + tid]; }
    __syncthreads();
    const float* va = vals + (size_t)a * NMEM * DIM;
    float acc0 = 0.f, acc1 = 0.f;
    for (int k = 0; k < KNB; ++k) {
        const float* vr = va + (size_t)il[k] * DIM;
        acc0 = fmaf(wl[k], vr[tid], acc0);
        acc1 = fmaf(wl[k], vr[tid + 256], acc1);
    }
    emb_out[b * DIM + tid] = acc0;
    emb_out[b * DIM + tid + 256] = acc1;
    eb_out[b * DIM + tid] = bf16rn(acc0);
    eb_out[b * DIM + tid + 256] = bf16rn(acc1);
    xs[tid] = acc0; xs[tid + 256] = acc1;
    red[tid] = acc0 * acc0 + acc1 * acc1;
    __syncthreads();
    for (int s = 128; s > 0; s >>= 1) { if (tid < s) red[tid] += red[tid + s]; __syncthreads(); }
    if (tid == 0) qn_out[b] = red[0];
    float acc = b1[tid];
    #pragma unroll 8
    for (int d = 0; d < DIM; ++d) acc = fmaf(xs[d], w1[d * H1N + tid], acc);
    h1[tid] = acc > 0.f ? acc : expm1f(acc);
    __syncthreads();
    if (tid < H2N) {
        float a2 = b2[tid];
        #pragma unroll 8
        for (int d = 0; d < H1N; ++d) a2 = fmaf(h1[d], w2[d * H2N + tid], a2);
        h2[tid] = a2 > 0.f ? a2 : expm1f(a2);
    }
    __syncthreads();
    if (tid < 5) {
        float p = b3[tid];
        for (int d = 0; d < H2N; ++d) p = fmaf(h2[d], w3[d * 5 + tid], p);
        float o = p;
        if (tid == 1) o = 1.0f / (1.0f + expf(-p));
        out[b * (6 * 5) + (step + 1) * 5 + tid] = o;
    }
}

// ---------- standalone MLP for step 0 ----------
__global__ __launch_bounds__(256)
void predict_kernel(const float* __restrict__ emb, const float* __restrict__ w1,
                    const float* __restrict__ b1, const float* __restrict__ w2,
                    const float* __restrict__ b2, const float* __restrict__ w3,
                    const float* __restrict__ b3, float* __restrict__ out, int step) {
    int b = blockIdx.x, tid = threadIdx.x;
    __shared__ float xs[DIM];
    __shared__ float h1[H1N];
    __shared__ float h2[H2N];
    xs[tid] = emb[(size_t)b * DIM + tid];
    xs[tid + 256] = emb[(size_t)b * DIM + tid + 256];
    __syncthreads();
    float acc = b1[tid];
    #pragma unroll 8
    for (int d = 0; d < DIM; ++d) acc = fmaf(xs[d], w1[d * H1N + tid], acc);
    h1[tid] = acc > 0.f ? acc : expm1f(acc);
    __syncthreads();
    if (tid < H2N) {
        float a2 = b2[tid];
        #pragma unroll 8
        for (int d = 0; d < H1N; ++d) a2 = fmaf(h1[d], w2[d * H2N + tid], a2);
        h2[tid] = a2 > 0.f ? a2 : expm1f(a2);
    }
    __syncthreads();
    if (tid < 5) {
        float p = b3[tid];
        for (int d = 0; d < H2N; ++d) p = fmaf(h2[d], w3[d * 5 + tid], p);
        float o = p;
        if (tid == 1) o = 1.0f / (1.0f + expf(-p));
        out[b * (6 * 5) + step * 5 + tid] = o;
    }
}

extern "C" void kernel_launch(void* const* d_in, const int* in_sizes, int n_in,
                              void* d_out, int out_size, void* d_ws, size_t ws_size,
                              hipStream_t stream) {
    const float* x        = (const float*)d_in[0];
    const int*   actions  = (const int*)d_in[1];
    const float* mem_keys = (const float*)d_in[2];
    const float* mem_vals = (const float*)d_in[3];
    const float* w1 = (const float*)d_in[4];
    const float* b1 = (const float*)d_in[5];
    const float* w2 = (const float*)d_in[6];
    const float* b2 = (const float*)d_in[7];
    const float* w3 = (const float*)d_in[8];
    const float* b3 = (const float*)d_in[9];
    float* out = (float*)d_out;

    // workspace layout (bytes; 16B-aligned blocks)
    char* W = (char*)d_ws;
    unsigned short* distb = (unsigned short*)W;                 // 12,800,000
    unsigned short* eb    = (unsigned short*)(W + 12800000);    //    262,144
    float* kn   = (float*)(W + 13062144);                       //    300,032
    float* qnb  = (float*)(W + 13362176);                       //      1,024
    float* emb  = (float*)(W + 13363200);                       //    524,288
    int*   perm = (int*)(W + 13887488);                         //     15,360
    int*   cntb = (int*)(W + 13902848);                         //        128
    int*   idxb = (int*)(W + 13902976);                         //     51,200
    float* wb   = (float*)(W + 13954176);                       //     51,200
    float* psum = (float*)(W + 14005376);                       //    401,408
    float* psq  = (float*)(W + 14406784);                       //    401,408
    float* Tb   = (float*)(W + 14808192);                       //      1,024
    float* sdb  = (float*)(W + 14809216);                       //      1,024  (end ~14.8 MB)

    knorm_kernel<<<dim3((NACT * NMEM + 3) / 4), dim3(256), 0, stream>>>(mem_keys, kn, NACT * NMEM);
    prep_x_kernel<<<dim3((BATCH + 3) / 4), dim3(256), 0, stream>>>(x, eb, qnb, BATCH);
    predict_kernel<<<dim3(BATCH), dim3(256), 0, stream>>>(x, w1, b1, w2, b2, w3, b3, out, 0);
    group_all_kernel<<<dim3(NSTEPS), dim3(256), 0, stream>>>(actions, perm, cntb);

    const float* cur = x;
    for (int j = 0; j < NSTEPS; ++j) {
        dist_kernel<<<dim3(NACT * 2, NYT), dim3(256), 0, stream>>>(
            eb, mem_keys, kn, perm + j * NACT * BATCH, cntb + j * 4, distb, psum, psq);
        thresh_kernel<<<dim3(BATCH / 4), dim3(256), 0, stream>>>(psum, psq, Tb, sdb);
        select_kernel<<<dim3(BATCH), dim3(1024), 0, stream>>>(
            distb, cur, mem_keys, kn, qnb, Tb, sdb, actions, j, idxb, wb);
        gp_kernel<<<dim3(BATCH), dim3(256), 0, stream>>>(
            mem_vals, idxb, wb, actions, j, emb, eb, qnb, w1, b1, w2, b2, w3, b3, out);
        cur = emb;
    }
}

// Round 9
// 922.394 us; speedup vs baseline: 1.0595x; 1.0595x over previous
//
#include <hip/hip_runtime.h>

#define BATCH 256
#define DIM 512
#define NACT 3
#define NMEM 25000
#define KNB 50
#define H1N 256
#define H2N 128
#define NSTEPS 5
#define KDELTA 0.001f

#define TB 128
#define TN 64
#define BK 64
#define NYT ((NMEM + TN - 1) / TN)   // 391 n-tiles (25000/64 = 390.6 -> 391)

#define CAP 2048           // candidate buffer cap

typedef __attribute__((ext_vector_type(8))) short short8;
typedef __attribute__((ext_vector_type(4))) float f32x4;

__device__ __forceinline__ unsigned short bf16rn(float f) {
    unsigned u = __float_as_uint(f);
    u += 0x7FFFu + ((u >> 16) & 1u);
    return (unsigned short)(u >> 16);
}
__device__ __forceinline__ float blo(unsigned u) { return __uint_as_float(u << 16); }
__device__ __forceinline__ float bhi(unsigned u) { return __uint_as_float(u & 0xFFFF0000u); }

// ---------- key row norms (one wave per row) ----------
__global__ __launch_bounds__(256)
void knorm_kernel(const float* __restrict__ rows, float* __restrict__ kn, int nrows) {
    int wave = threadIdx.x >> 6, lane = threadIdx.x & 63;
    int r = blockIdx.x * 4 + wave;
    if (r >= nrows) return;
    const float* p = rows + (size_t)r * DIM;
    float4 v0 = *(const float4*)(p + lane * 8);
    float4 v1 = *(const float4*)(p + lane * 8 + 4);
    float s = v0.x*v0.x + v0.y*v0.y + v0.z*v0.z + v0.w*v0.w
            + v1.x*v1.x + v1.y*v1.y + v1.z*v1.z + v1.w*v1.w;
    for (int off = 32; off; off >>= 1) s += __shfl_down(s, off);
    if (lane == 0) kn[r] = s;
}

// ---------- prep x: bf16 copy + qn ----------
__global__ __launch_bounds__(256)
void prep_x_kernel(const float* __restrict__ rows, unsigned short* __restrict__ eb,
                   float* __restrict__ qn, int nrows) {
    int wave = threadIdx.x >> 6, lane = threadIdx.x & 63;
    int r = blockIdx.x * 4 + wave;
    if (r >= nrows) return;
    const float* p = rows + (size_t)r * DIM;
    float4 v0 = *(const float4*)(p + lane * 8);
    float4 v1 = *(const float4*)(p + lane * 8 + 4);
    float f[8] = {v0.x, v0.y, v0.z, v0.w, v1.x, v1.y, v1.z, v1.w};
    short8 hv;
    float s = 0.f;
    #pragma unroll
    for (int i = 0; i < 8; ++i) { hv[i] = (short)bf16rn(f[i]); s += f[i] * f[i]; }
    *(short8*)(eb + (size_t)r * DIM + lane * 8) = hv;
    for (int off = 32; off; off >>= 1) s += __shfl_down(s, off);
    if (lane == 0) qn[r] = s;
}

// ---------- group batch rows by action, all steps in one launch ----------
__global__ __launch_bounds__(256)
void group_all_kernel(const int* __restrict__ actions,
                      int* __restrict__ perm, int* __restrict__ cnt) {
    int step = blockIdx.x;
    __shared__ int lcnt[NACT];
    __shared__ int lperm[NACT * BATCH];
    int tid = threadIdx.x;
    if (tid < NACT) lcnt[tid] = 0;
    __syncthreads();
    int a = actions[tid * NSTEPS + step];
    int pos = atomicAdd(&lcnt[a], 1);
    lperm[a * BATCH + pos] = tid;
    __syncthreads();
    if (tid < NACT) cnt[step * 4 + tid] = lcnt[tid];
    for (int aa = 0; aa < NACT; ++aa) {
        int c = lcnt[aa];
        int f = (c > 0) ? lperm[aa * BATCH] : 0;
        for (int i = c + tid; i < BATCH; i += 256) lperm[aa * BATCH + i] = f;
    }
    __syncthreads();
    for (int i = tid; i < NACT * BATCH; i += 256)
        perm[step * NACT * BATCH + i] = lperm[i];
}

// ---------- approx distance GEMM: bf16 MFMA, dbuf LDS, async-stage, 128x64 tile ----------
// also emits per-row partial sums/sumsq for the threshold stats
__global__ __launch_bounds__(256)
void dist_kernel(const unsigned short* __restrict__ eb, const float* __restrict__ keys,
                 const float* __restrict__ kn, const int* __restrict__ perm,
                 const int* __restrict__ cnt, unsigned short* __restrict__ dist,
                 float* __restrict__ psum, float* __restrict__ psq) {
    int a = blockIdx.x >> 1;
    int tb0 = (blockIdx.x & 1) * TB;
    int c = cnt[a];
    if (tb0 >= c) return;
    int n0 = blockIdx.y * TN;

    __shared__ __align__(16) unsigned short Qh[2][TB][BK];
    __shared__ __align__(16) unsigned short Kh[2][TN][BK];
    __shared__ int rows[TB];

    int tid = threadIdx.x;
    if (tid < TB) {
        int i = tb0 + tid;
        rows[tid] = perm[a * BATCH + (i < c ? i : 0)];
    }
    __syncthreads();

    int lane = tid & 63, wave = tid >> 6;
    int wm = wave >> 1, wn = wave & 1;

    f32x4 acc[4][2] = {};

    const int qr = tid >> 1, qc = (tid & 1) * 32, qswz = (qr & 7) * 8;
    const int kr = tid >> 2, kc = (tid & 3) * 16, kswz = (kr & 7) * 8;
    int krow = (n0 + kr < NMEM) ? (n0 + kr) : (NMEM - 1);
    const unsigned short* qsrc = eb + (size_t)rows[qr] * DIM + qc;
    const float* ksrc = keys + (size_t)a * NMEM * DIM + (size_t)krow * DIM + kc;

    short8 qv[4];
    float4 kf[4];

    // prologue: load + write chunk 0
    #pragma unroll
    for (int j = 0; j < 4; ++j) qv[j] = *(const short8*)(qsrc + j * 8);
    #pragma unroll
    for (int j = 0; j < 4; ++j) kf[j] = *(const float4*)(ksrc + j * 4);
    #pragma unroll
    for (int j = 0; j < 4; ++j) *(short8*)&Qh[0][qr][(qc + j * 8) ^ qswz] = qv[j];
    {
        short8 h0, h1;
        #pragma unroll
        for (int i = 0; i < 4; ++i) {
            h0[i]   = (short)bf16rn(kf[0][i]); h0[i+4] = (short)bf16rn(kf[1][i]);
            h1[i]   = (short)bf16rn(kf[2][i]); h1[i+4] = (short)bf16rn(kf[3][i]);
        }
        *(short8*)&Kh[0][kr][(kc + 0) ^ kswz] = h0;
        *(short8*)&Kh[0][kr][(kc + 8) ^ kswz] = h1;
    }
    __syncthreads();

    int cur = 0;
    for (int it = 0; it < DIM / BK; ++it) {
        // issue next chunk's global loads (hide latency under MFMA phase)
        if (it < DIM / BK - 1) {
            int d0 = (it + 1) * BK;
            #pragma unroll
            for (int j = 0; j < 4; ++j) qv[j] = *(const short8*)(qsrc + d0 + j * 8);
            #pragma unroll
            for (int j = 0; j < 4; ++j) kf[j] = *(const float4*)(ksrc + d0 + j * 4);
        }
        // MFMA phase on buffer cur
        #pragma unroll
        for (int kk = 0; kk < BK; kk += 32) {
            int kcol = kk + (lane >> 4) * 8;
            short8 av[4], bv[2];
            #pragma unroll
            for (int mf = 0; mf < 4; ++mf) {
                int m = wm * 64 + mf * 16 + (lane & 15);
                av[mf] = *(const short8*)&Qh[cur][m][kcol ^ ((m & 7) * 8)];
            }
            #pragma unroll
            for (int nf = 0; nf < 2; ++nf) {
                int n = wn * 32 + nf * 16 + (lane & 15);
                bv[nf] = *(const short8*)&Kh[cur][n][kcol ^ ((n & 7) * 8)];
            }
            #pragma unroll
            for (int mf = 0; mf < 4; ++mf)
                #pragma unroll
                for (int nf = 0; nf < 2; ++nf)
                    acc[mf][nf] = __builtin_amdgcn_mfma_f32_16x16x32_bf16(av[mf], bv[nf], acc[mf][nf], 0, 0, 0);
        }
        // write next chunk into the other buffer (vmcnt wait lands here, after MFMAs)
        if (it < DIM / BK - 1) {
            #pragma unroll
            for (int j = 0; j < 4; ++j) *(short8*)&Qh[cur ^ 1][qr][(qc + j * 8) ^ qswz] = qv[j];
            short8 h0, h1;
            #pragma unroll
            for (int i = 0; i < 4; ++i) {
                h0[i]   = (short)bf16rn(kf[0][i]); h0[i+4] = (short)bf16rn(kf[1][i]);
                h1[i]   = (short)bf16rn(kf[2][i]); h1[i+4] = (short)bf16rn(kf[3][i]);
            }
            *(short8*)&Kh[cur ^ 1][kr][(kc + 0) ^ kswz] = h0;
            *(short8*)&Kh[cur ^ 1][kr][(kc + 8) ^ kswz] = h1;
            __syncthreads();
        }
        cur ^= 1;
    }

    // ---- epilogue: store bf16 dist + per-row stats partials ----
    // C/D layout: col=lane&15, row=(lane>>4)*4+reg
    int nn[2]; float knv[2]; bool nvalid[2];
    #pragma unroll
    for (int nf = 0; nf < 2; ++nf) {
        nn[nf] = n0 + wn * 32 + nf * 16 + (lane & 15);
        nvalid[nf] = nn[nf] < NMEM;
        knv[nf] = nvalid[nf] ? kn[a * NMEM + nn[nf]] : 0.f;
    }
    int slot = (blockIdx.y * 2 + wn) * BATCH;
    #pragma unroll
    for (int mf = 0; mf < 4; ++mf) {
        #pragma unroll
        for (int r = 0; r < 4; ++r) {
            int m = wm * 64 + mf * 16 + (lane >> 4) * 4 + r;
            int b = rows[m];
            float s = 0.f, q2 = 0.f;
            #pragma unroll
            for (int nf = 0; nf < 2; ++nf) {
                if (nvalid[nf]) {
                    float d = knv[nf] - 2.0f * acc[mf][nf][r];
                    dist[(size_t)b * NMEM + nn[nf]] = bf16rn(d);
                    s += d; q2 += d * d;
                }
            }
            #pragma unroll
            for (int x = 1; x < 16; x <<= 1) { s += __shfl_xor(s, x); q2 += __shfl_xor(q2, x); }
            if ((lane & 15) == 0) { psum[slot + b] = s; psq[slot + b] = q2; }
        }
    }
}

// ---------- threshold from stats partials (one wave per row) ----------
__global__ __launch_bounds__(256)
void thresh_kernel(const float* __restrict__ psum, const float* __restrict__ psq,
                   float* __restrict__ Tb, float* __restrict__ sdb) {
    int wave = threadIdx.x >> 6, lane = threadIdx.x & 63;
    int b = blockIdx.x * 4 + wave;
    float s = 0.f, q = 0.f;
    for (int i = lane; i < NYT * 2; i += 64) {
        s += psum[i * BATCH + b];
        q += psq[i * BATCH + b];
    }
    for (int off = 32; off; off >>= 1) { s += __shfl_down(s, off); q += __shfl_down(q, off); }
    if (lane == 0) {
        float mean = s / (float)NMEM;
        float var = q / (float)NMEM - mean * mean;
        float sd = sqrtf(fmaxf(var, 0.f));
        Tb[b] = mean - 2.575f * sd;
        sdb[b] = sd;
    }
}

// ---------- select: candidate collect (threshold) -> exact f32 refine -> top-50 ----------
__global__ __launch_bounds__(1024)
void select_kernel(const unsigned short* __restrict__ dist, const float* __restrict__ emb,
                   const float* __restrict__ keys, const float* __restrict__ kn,
                   const float* __restrict__ qn, const float* __restrict__ Tb,
                   const float* __restrict__ sdb, const int* __restrict__ actions,
                   int step, int* __restrict__ idx_out, float* __restrict__ w_out) {
    __shared__ float qs[DIM];
    __shared__ unsigned cntS;
    __shared__ int candb[CAP];
    __shared__ float dex[CAP];
    __shared__ float wsel[KNB];
    __shared__ int   isel[KNB];
    __shared__ float wsumS;

    int b = blockIdx.x, tid = threadIdx.x;
    const uint4* d8 = (const uint4*)(dist + (size_t)b * NMEM);   // 8 bf16 per uint4

    if (tid < 128) *(float4*)&qs[tid * 4] = *(const float4*)(emb + (size_t)b * DIM + tid * 4);

    // ---- phase 1: collect all d < T (widen if under 128) ----
    float T = Tb[b], sd = sdb[b];
    for (int it = 0; it < 8; ++it) {
        if (tid == 0) cntS = 0;
        __syncthreads();
        for (int i = tid; i < NMEM / 8; i += 1024) {
            uint4 v = d8[i];
            int n = i * 8;
            float f[8] = {blo(v.x), bhi(v.x), blo(v.y), bhi(v.y),
                          blo(v.z), bhi(v.z), blo(v.w), bhi(v.w)};
            #pragma unroll
            for (int k = 0; k < 8; ++k)
                if (f[k] < T) { unsigned p = atomicAdd(&cntS, 1u); if (p < CAP) candb[p] = n + k; }
        }
        __syncthreads();
        if (cntS >= 128) break;
        T += 0.6f * sd;
        __syncthreads();
    }
    int C = (int)cntS; if (C > CAP) C = CAP;

    // ---- phase 2: exact f32 distances (8 threads/cand, interleaved dims: conflict-free) ----
    int a = actions[b * NSTEPS + step];
    float qnb = qn[b];
    const float* keysA = keys + (size_t)a * NMEM * DIM;
    int cslot = tid >> 3, sub = tid & 7;
    int sweeps = (C + 127) >> 7;
    for (int sw = 0; sw < sweeps; ++sw) {
        int ci = (sw << 7) + cslot;
        float dot = 0.f;
        int n = 0;
        if (ci < C) {
            n = candb[ci];
            const float* kr = keysA + (size_t)n * DIM;
            #pragma unroll
            for (int k = 0; k < 16; ++k) {
                int o = sub * 4 + k * 32;
                float4 kv = *(const float4*)(kr + o);
                dot = fmaf(kv.x, qs[o+0], dot);
                dot = fmaf(kv.y, qs[o+1], dot);
                dot = fmaf(kv.z, qs[o+2], dot);
                dot = fmaf(kv.w, qs[o+3], dot);
            }
        }
        dot += __shfl_xor(dot, 1);
        dot += __shfl_xor(dot, 2);
        dot += __shfl_xor(dot, 4);
        if (ci < C && sub == 0)
            dex[ci] = qnb + kn[a * NMEM + n] - 2.0f * dot;
    }
    __syncthreads();

    // ---- phase 3: exact (d, idx) rank; top-50 ----
    for (int ci = tid; ci < C; ci += 1024) {
        float di = dex[ci]; int ni = candb[ci];
        int rank = 0;
        for (int j = 0; j < C; ++j) {
            float dj = dex[j];
            rank += (dj < di || (dj == di && candb[j] < ni)) ? 1 : 0;
        }
        if (rank < KNB) { wsel[rank] = 1.0f / (di + KDELTA); isel[rank] = ni; }
    }
    __syncthreads();
    if (tid == 0) {
        float ssum = 0.f;
        for (int i = 0; i < KNB; ++i) ssum += wsel[i];
        wsumS = ssum;
    }
    __syncthreads();
    if (tid < KNB) {
        w_out[b * KNB + tid] = wsel[tid] / wsumS;
        idx_out[b * KNB + tid] = isel[tid];
    }
}

// ---------- fused gather + next-qn + bf16 emb + 3-layer MLP ----------
__global__ __launch_bounds__(256)
void gp_kernel(const float* __restrict__ vals, const int* __restrict__ idx,
               const float* __restrict__ w, const int* __restrict__ actions, int step,
               float* __restrict__ emb_out, unsigned short* __restrict__ eb_out,
               float* __restrict__ qn_out,
               const float* __restrict__ w1, const float* __restrict__ b1,
               const float* __restrict__ w2, const float* __restrict__ b2,
               const float* __restrict__ w3, const float* __restrict__ b3,
               float* __restrict__ out) {
    int b = blockIdx.x, tid = threadIdx.x;
    int a = actions[b * NSTEPS + step];
    __shared__ float wl[KNB];
    __shared__ int il[KNB];
    __shared__ float red[256];
    __shared__ float xs[DIM];
    __shared__ float h1[H1N];
    __shared__ float h2[H2N];
    if (tid < KNB) { wl[tid] = w[b * KNB + tid]; il[tid] = idx[b * KNB + tid]; }
    __syncthreads();
    const float* va = vals + (size_t)a * NMEM * DIM;
    float acc0 = 0.f, acc1 = 0.f;
    for (int k = 0; k < KNB; ++k) {
        const float* vr = va + (size_t)il[k] * DIM;
        acc0 = fmaf(wl[k], vr[tid], acc0);
        acc1 = fmaf(wl[k], vr[tid + 256], acc1);
    }
    emb_out[b * DIM + tid] = acc0;
    emb_out[b * DIM + tid + 256] = acc1;
    eb_out[b * DIM + tid] = bf16rn(acc0);
    eb_out[b * DIM + tid + 256] = bf16rn(acc1);
    xs[tid] = acc0; xs[tid + 256] = acc1;
    red[tid] = acc0 * acc0 + acc1 * acc1;
    __syncthreads();
    for (int s = 128; s > 0; s >>= 1) { if (tid < s) red[tid] += red[tid + s]; __syncthreads(); }
    if (tid == 0) qn_out[b] = red[0];
    float acc = b1[tid];
    #pragma unroll 8
    for (int d = 0; d < DIM; ++d) acc = fmaf(xs[d], w1[d * H1N + tid], acc);
    h1[tid] = acc > 0.f ? acc : expm1f(acc);
    __syncthreads();
    if (tid < H2N) {
        float a2 = b2[tid];
        #pragma unroll 8
        for (int d = 0; d < H1N; ++d) a2 = fmaf(h1[d], w2[d * H2N + tid], a2);
        h2[tid] = a2 > 0.f ? a2 : expm1f(a2);
    }
    __syncthreads();
    if (tid < 5) {
        float p = b3[tid];
        for (int d = 0; d < H2N; ++d) p = fmaf(h2[d], w3[d * 5 + tid], p);
        float o = p;
        if (tid == 1) o = 1.0f / (1.0f + expf(-p));
        out[b * (6 * 5) + (step + 1) * 5 + tid] = o;
    }
}

// ---------- standalone MLP for step 0 ----------
__global__ __launch_bounds__(256)
void predict_kernel(const float* __restrict__ emb, const float* __restrict__ w1,
                    const float* __restrict__ b1, const float* __restrict__ w2,
                    const float* __restrict__ b2, const float* __restrict__ w3,
                    const float* __restrict__ b3, float* __restrict__ out, int step) {
    int b = blockIdx.x, tid = threadIdx.x;
    __shared__ float xs[DIM];
    __shared__ float h1[H1N];
    __shared__ float h2[H2N];
    xs[tid] = emb[(size_t)b * DIM + tid];
    xs[tid + 256] = emb[(size_t)b * DIM + tid + 256];
    __syncthreads();
    float acc = b1[tid];
    #pragma unroll 8
    for (int d = 0; d < DIM; ++d) acc = fmaf(xs[d], w1[d * H1N + tid], acc);
    h1[tid] = acc > 0.f ? acc : expm1f(acc);
    __syncthreads();
    if (tid < H2N) {
        float a2 = b2[tid];
        #pragma unroll 8
        for (int d = 0; d < H1N; ++d) a2 = fmaf(h1[d], w2[d * H2N + tid], a2);
        h2[tid] = a2 > 0.f ? a2 : expm1f(a2);
    }
    __syncthreads();
    if (tid < 5) {
        float p = b3[tid];
        for (int d = 0; d < H2N; ++d) p = fmaf(h2[d], w3[d * 5 + tid], p);
        float o = p;
        if (tid == 1) o = 1.0f / (1.0f + expf(-p));
        out[b * (6 * 5) + step * 5 + tid] = o;
    }
}

extern "C" void kernel_launch(void* const* d_in, const int* in_sizes, int n_in,
                              void* d_out, int out_size, void* d_ws, size_t ws_size,
                              hipStream_t stream) {
    const float* x        = (const float*)d_in[0];
    const int*   actions  = (const int*)d_in[1];
    const float* mem_keys = (const float*)d_in[2];
    const float* mem_vals = (const float*)d_in[3];
    const float* w1 = (const float*)d_in[4];
    const float* b1 = (const float*)d_in[5];
    const float* w2 = (const float*)d_in[6];
    const float* b2 = (const float*)d_in[7];
    const float* w3 = (const float*)d_in[8];
    const float* b3 = (const float*)d_in[9];
    float* out = (float*)d_out;

    // workspace layout (bytes; 16B-aligned blocks)
    char* W = (char*)d_ws;
    unsigned short* distb = (unsigned short*)W;                 // 12,800,000
    unsigned short* eb    = (unsigned short*)(W + 12800000);    //    262,144
    float* kn   = (float*)(W + 13062144);                       //    300,032
    float* qnb  = (float*)(W + 13362176);                       //      1,024
    float* emb  = (float*)(W + 13363200);                       //    524,288
    int*   perm = (int*)(W + 13887488);                         //     15,360
    int*   cntb = (int*)(W + 13902848);                         //        128
    int*   idxb = (int*)(W + 13902976);                         //     51,200
    float* wb   = (float*)(W + 13954176);                       //     51,200
    float* psum = (float*)(W + 14005376);                       //    802,816 (782*256*4 < this)
    float* psq  = (float*)(W + 14808192);                       //    802,816
    float* Tb   = (float*)(W + 15611008);                       //      1,024
    float* sdb  = (float*)(W + 15612032);                       //      1,024  (end ~15.6 MB)

    knorm_kernel<<<dim3((NACT * NMEM + 3) / 4), dim3(256), 0, stream>>>(mem_keys, kn, NACT * NMEM);
    prep_x_kernel<<<dim3((BATCH + 3) / 4), dim3(256), 0, stream>>>(x, eb, qnb, BATCH);
    predict_kernel<<<dim3(BATCH), dim3(256), 0, stream>>>(x, w1, b1, w2, b2, w3, b3, out, 0);
    group_all_kernel<<<dim3(NSTEPS), dim3(256), 0, stream>>>(actions, perm, cntb);

    const float* cur = x;
    for (int j = 0; j < NSTEPS; ++j) {
        dist_kernel<<<dim3(NACT * 2, NYT), dim3(256), 0, stream>>>(
            eb, mem_keys, kn, perm + j * NACT * BATCH, cntb + j * 4, distb, psum, psq);
        thresh_kernel<<<dim3(BATCH / 4), dim3(256), 0, stream>>>(psum, psq, Tb, sdb);
        select_kernel<<<dim3(BATCH), dim3(1024), 0, stream>>>(
            distb, cur, mem_keys, kn, qnb, Tb, sdb, actions, j, idxb, wb);
        gp_kernel<<<dim3(BATCH), dim3(256), 0, stream>>>(
            mem_vals, idxb, wb, actions, j, emb, eb, qnb, w1, b1, w2, b2, w3, b3, out);
        cur = emb;
    }
}

// Round 10
// 720.314 us; speedup vs baseline: 1.3567x; 1.2805x over previous
//
#include <hip/hip_runtime.h>

#define BATCH 256
#define DIM 512
#define NACT 3
#define NMEM 25000
#define KNB 50
#define H1N 256
#define H2N 128
#define NSTEPS 5
#define KDELTA 0.001f

#define TB 128
#define TN 64
#define BK 64
#define NYT ((NMEM + TN - 1) / TN)   // 391 n-tiles

#define CAP 2048           // candidate buffer cap

typedef __attribute__((ext_vector_type(8))) short short8;
typedef __attribute__((ext_vector_type(4))) float f32x4;

__device__ __forceinline__ unsigned short bf16rn(float f) {
    unsigned u = __float_as_uint(f);
    u += 0x7FFFu + ((u >> 16) & 1u);
    return (unsigned short)(u >> 16);
}
__device__ __forceinline__ float blo(unsigned u) { return __uint_as_float(u << 16); }
__device__ __forceinline__ float bhi(unsigned u) { return __uint_as_float(u & 0xFFFF0000u); }

// ---------- prep keys: f32 -> bf16 copy + row norms (one wave per row) ----------
__global__ __launch_bounds__(256)
void prep_keys_kernel(const float* __restrict__ rows, unsigned short* __restrict__ kb,
                      float* __restrict__ kn, int nrows) {
    int wave = threadIdx.x >> 6, lane = threadIdx.x & 63;
    int r = blockIdx.x * 4 + wave;
    if (r >= nrows) return;
    const float* p = rows + (size_t)r * DIM;
    float4 v0 = *(const float4*)(p + lane * 8);
    float4 v1 = *(const float4*)(p + lane * 8 + 4);
    float f[8] = {v0.x, v0.y, v0.z, v0.w, v1.x, v1.y, v1.z, v1.w};
    short8 hv;
    float s = 0.f;
    #pragma unroll
    for (int i = 0; i < 8; ++i) { hv[i] = (short)bf16rn(f[i]); s += f[i] * f[i]; }
    *(short8*)(kb + (size_t)r * DIM + lane * 8) = hv;
    for (int off = 32; off; off >>= 1) s += __shfl_down(s, off);
    if (lane == 0) kn[r] = s;
}

// ---------- prep x: bf16 copy + qn ----------
__global__ __launch_bounds__(256)
void prep_x_kernel(const float* __restrict__ rows, unsigned short* __restrict__ eb,
                   float* __restrict__ qn, int nrows) {
    int wave = threadIdx.x >> 6, lane = threadIdx.x & 63;
    int r = blockIdx.x * 4 + wave;
    if (r >= nrows) return;
    const float* p = rows + (size_t)r * DIM;
    float4 v0 = *(const float4*)(p + lane * 8);
    float4 v1 = *(const float4*)(p + lane * 8 + 4);
    float f[8] = {v0.x, v0.y, v0.z, v0.w, v1.x, v1.y, v1.z, v1.w};
    short8 hv;
    float s = 0.f;
    #pragma unroll
    for (int i = 0; i < 8; ++i) { hv[i] = (short)bf16rn(f[i]); s += f[i] * f[i]; }
    *(short8*)(eb + (size_t)r * DIM + lane * 8) = hv;
    for (int off = 32; off; off >>= 1) s += __shfl_down(s, off);
    if (lane == 0) qn[r] = s;
}

// ---------- group batch rows by action, all steps in one launch ----------
__global__ __launch_bounds__(256)
void group_all_kernel(const int* __restrict__ actions,
                      int* __restrict__ perm, int* __restrict__ cnt) {
    int step = blockIdx.x;
    __shared__ int lcnt[NACT];
    __shared__ int lperm[NACT * BATCH];
    int tid = threadIdx.x;
    if (tid < NACT) lcnt[tid] = 0;
    __syncthreads();
    int a = actions[tid * NSTEPS + step];
    int pos = atomicAdd(&lcnt[a], 1);
    lperm[a * BATCH + pos] = tid;
    __syncthreads();
    if (tid < NACT) cnt[step * 4 + tid] = lcnt[tid];
    for (int aa = 0; aa < NACT; ++aa) {
        int c = lcnt[aa];
        int f = (c > 0) ? lperm[aa * BATCH] : 0;
        for (int i = c + tid; i < BATCH; i += 256) lperm[aa * BATCH + i] = f;
    }
    __syncthreads();
    for (int i = tid; i < NACT * BATCH; i += 256)
        perm[step * NACT * BATCH + i] = lperm[i];
}

// ---------- approx distance GEMM: bf16 MFMA, bf16 keys, dbuf LDS, async-stage ----------
// grid = (NACT, NYT); all blocks active; b-tiles looped inside (2nd iter ~never runs)
__global__ __launch_bounds__(256)
void dist_kernel(const unsigned short* __restrict__ eb, const unsigned short* __restrict__ kb,
                 const float* __restrict__ kn, const int* __restrict__ perm,
                 const int* __restrict__ cnt, unsigned short* __restrict__ dist,
                 float* __restrict__ psum, float* __restrict__ psq) {
    int a = blockIdx.x;
    int c = cnt[a];
    int n0 = blockIdx.y * TN;

    __shared__ __align__(16) unsigned short Qh[2][TB][BK];
    __shared__ __align__(16) unsigned short Kh[2][TN][BK];
    __shared__ int rows[TB];

    int tid = threadIdx.x;
    int lane = tid & 63, wave = tid >> 6;
    int wm = wave >> 1, wn = wave & 1;

    const int qr = tid >> 1, qc = (tid & 1) * 32, qswz = (qr & 7) * 8;
    const int kr = tid >> 2, kc = (tid & 3) * 16, kswz = (kr & 7) * 8;
    int krow = (n0 + kr < NMEM) ? (n0 + kr) : (NMEM - 1);
    const unsigned short* ksrc = kb + ((size_t)a * NMEM + krow) * DIM + kc;

    int nn[2]; float knv[2]; bool nvalid[2];
    #pragma unroll
    for (int nf = 0; nf < 2; ++nf) {
        nn[nf] = n0 + wn * 32 + nf * 16 + (lane & 15);
        nvalid[nf] = nn[nf] < NMEM;
        knv[nf] = nvalid[nf] ? kn[a * NMEM + nn[nf]] : 0.f;
    }
    int slot = (blockIdx.y * 2 + wn) * BATCH;

    for (int tb0 = 0; tb0 < c; tb0 += TB) {
        __syncthreads();
        if (tid < TB) {
            int i = tb0 + tid;
            rows[tid] = perm[a * BATCH + (i < c ? i : 0)];
        }
        __syncthreads();

        const unsigned short* qsrc = eb + (size_t)rows[qr] * DIM + qc;
        f32x4 acc[4][2] = {};
        short8 qv[4], kv[2];

        // prologue: load + write chunk 0
        #pragma unroll
        for (int j = 0; j < 4; ++j) qv[j] = *(const short8*)(qsrc + j * 8);
        kv[0] = *(const short8*)(ksrc);
        kv[1] = *(const short8*)(ksrc + 8);
        #pragma unroll
        for (int j = 0; j < 4; ++j) *(short8*)&Qh[0][qr][(qc + j * 8) ^ qswz] = qv[j];
        *(short8*)&Kh[0][kr][(kc + 0) ^ kswz] = kv[0];
        *(short8*)&Kh[0][kr][(kc + 8) ^ kswz] = kv[1];
        __syncthreads();

        int cur = 0;
        for (int it = 0; it < DIM / BK; ++it) {
            // issue next chunk's global loads (hide latency under MFMA phase)
            if (it < DIM / BK - 1) {
                int d0 = (it + 1) * BK;
                #pragma unroll
                for (int j = 0; j < 4; ++j) qv[j] = *(const short8*)(qsrc + d0 + j * 8);
                kv[0] = *(const short8*)(ksrc + d0);
                kv[1] = *(const short8*)(ksrc + d0 + 8);
            }
            // MFMA phase on buffer cur
            #pragma unroll
            for (int kk = 0; kk < BK; kk += 32) {
                int kcol = kk + (lane >> 4) * 8;
                short8 av[4], bv[2];
                #pragma unroll
                for (int mf = 0; mf < 4; ++mf) {
                    int m = wm * 64 + mf * 16 + (lane & 15);
                    av[mf] = *(const short8*)&Qh[cur][m][kcol ^ ((m & 7) * 8)];
                }
                #pragma unroll
                for (int nf = 0; nf < 2; ++nf) {
                    int n = wn * 32 + nf * 16 + (lane & 15);
                    bv[nf] = *(const short8*)&Kh[cur][n][kcol ^ ((n & 7) * 8)];
                }
                #pragma unroll
                for (int mf = 0; mf < 4; ++mf)
                    #pragma unroll
                    for (int nf = 0; nf < 2; ++nf)
                        acc[mf][nf] = __builtin_amdgcn_mfma_f32_16x16x32_bf16(av[mf], bv[nf], acc[mf][nf], 0, 0, 0);
            }
            // write next chunk into the other buffer
            if (it < DIM / BK - 1) {
                #pragma unroll
                for (int j = 0; j < 4; ++j) *(short8*)&Qh[cur ^ 1][qr][(qc + j * 8) ^ qswz] = qv[j];
                *(short8*)&Kh[cur ^ 1][kr][(kc + 0) ^ kswz] = kv[0];
                *(short8*)&Kh[cur ^ 1][kr][(kc + 8) ^ kswz] = kv[1];
                __syncthreads();
            }
            cur ^= 1;
        }

        // ---- epilogue: store bf16 dist + per-row stats partials ----
        // C/D layout: col=lane&15, row=(lane>>4)*4+reg
        #pragma unroll
        for (int mf = 0; mf < 4; ++mf) {
            #pragma unroll
            for (int r = 0; r < 4; ++r) {
                int m = wm * 64 + mf * 16 + (lane >> 4) * 4 + r;
                int b = rows[m];
                float s = 0.f, q2 = 0.f;
                #pragma unroll
                for (int nf = 0; nf < 2; ++nf) {
                    if (nvalid[nf]) {
                        float d = knv[nf] - 2.0f * acc[mf][nf][r];
                        dist[(size_t)b * NMEM + nn[nf]] = bf16rn(d);
                        s += d; q2 += d * d;
                    }
                }
                #pragma unroll
                for (int x = 1; x < 16; x <<= 1) { s += __shfl_xor(s, x); q2 += __shfl_xor(q2, x); }
                if ((lane & 15) == 0) { psum[slot + b] = s; psq[slot + b] = q2; }
            }
        }
    }
}

// ---------- threshold from stats partials (one wave per row) ----------
__global__ __launch_bounds__(256)
void thresh_kernel(const float* __restrict__ psum, const float* __restrict__ psq,
                   float* __restrict__ Tb, float* __restrict__ sdb) {
    int wave = threadIdx.x >> 6, lane = threadIdx.x & 63;
    int b = blockIdx.x * 4 + wave;
    float s = 0.f, q = 0.f;
    for (int i = lane; i < NYT * 2; i += 64) {
        s += psum[i * BATCH + b];
        q += psq[i * BATCH + b];
    }
    for (int off = 32; off; off >>= 1) { s += __shfl_down(s, off); q += __shfl_down(q, off); }
    if (lane == 0) {
        float mean = s / (float)NMEM;
        float var = q / (float)NMEM - mean * mean;
        float sd = sqrtf(fmaxf(var, 0.f));
        Tb[b] = mean - 2.575f * sd;
        sdb[b] = sd;
    }
}

// ---------- select: candidate collect (threshold) -> exact f32 refine -> top-50 ----------
__global__ __launch_bounds__(1024)
void select_kernel(const unsigned short* __restrict__ dist, const float* __restrict__ emb,
                   const float* __restrict__ keys, const float* __restrict__ kn,
                   const float* __restrict__ qn, const float* __restrict__ Tb,
                   const float* __restrict__ sdb, const int* __restrict__ actions,
                   int step, int* __restrict__ idx_out, float* __restrict__ w_out) {
    __shared__ float qs[DIM];
    __shared__ unsigned cntS;
    __shared__ int candb[CAP];
    __shared__ float dex[CAP];
    __shared__ float wsel[KNB];
    __shared__ int   isel[KNB];
    __shared__ float wsumS;

    int b = blockIdx.x, tid = threadIdx.x;
    const uint4* d8 = (const uint4*)(dist + (size_t)b * NMEM);   // 8 bf16 per uint4

    if (tid < 128) *(float4*)&qs[tid * 4] = *(const float4*)(emb + (size_t)b * DIM + tid * 4);

    // ---- phase 1: collect all d < T (widen if under 128) ----
    float T = Tb[b], sd = sdb[b];
    for (int it = 0; it < 8; ++it) {
        if (tid == 0) cntS = 0;
        __syncthreads();
        for (int i = tid; i < NMEM / 8; i += 1024) {
            uint4 v = d8[i];
            int n = i * 8;
            float f[8] = {blo(v.x), bhi(v.x), blo(v.y), bhi(v.y),
                          blo(v.z), bhi(v.z), blo(v.w), bhi(v.w)};
            #pragma unroll
            for (int k = 0; k < 8; ++k)
                if (f[k] < T) { unsigned p = atomicAdd(&cntS, 1u); if (p < CAP) candb[p] = n + k; }
        }
        __syncthreads();
        if (cntS >= 128) break;
        T += 0.6f * sd;
        __syncthreads();
    }
    int C = (int)cntS; if (C > CAP) C = CAP;

    // ---- phase 2: exact f32 distances (8 threads/cand, interleaved dims: conflict-free) ----
    int a = actions[b * NSTEPS + step];
    float qnb = qn[b];
    const float* keysA = keys + (size_t)a * NMEM * DIM;
    int cslot = tid >> 3, sub = tid & 7;
    int sweeps = (C + 127) >> 7;
    for (int sw = 0; sw < sweeps; ++sw) {
        int ci = (sw << 7) + cslot;
        float dot = 0.f;
        int n = 0;
        if (ci < C) {
            n = candb[ci];
            const float* kr = keysA + (size_t)n * DIM;
            #pragma unroll
            for (int k = 0; k < 16; ++k) {
                int o = sub * 4 + k * 32;
                float4 kv = *(const float4*)(kr + o);
                dot = fmaf(kv.x, qs[o+0], dot);
                dot = fmaf(kv.y, qs[o+1], dot);
                dot = fmaf(kv.z, qs[o+2], dot);
                dot = fmaf(kv.w, qs[o+3], dot);
            }
        }
        dot += __shfl_xor(dot, 1);
        dot += __shfl_xor(dot, 2);
        dot += __shfl_xor(dot, 4);
        if (ci < C && sub == 0)
            dex[ci] = qnb + kn[a * NMEM + n] - 2.0f * dot;
    }
    __syncthreads();

    // ---- phase 3: exact (d, idx) rank; top-50 ----
    for (int ci = tid; ci < C; ci += 1024) {
        float di = dex[ci]; int ni = candb[ci];
        int rank = 0;
        for (int j = 0; j < C; ++j) {
            float dj = dex[j];
            rank += (dj < di || (dj == di && candb[j] < ni)) ? 1 : 0;
        }
        if (rank < KNB) { wsel[rank] = 1.0f / (di + KDELTA); isel[rank] = ni; }
    }
    __syncthreads();
    if (tid == 0) {
        float ssum = 0.f;
        for (int i = 0; i < KNB; ++i) ssum += wsel[i];
        wsumS = ssum;
    }
    __syncthreads();
    if (tid < KNB) {
        w_out[b * KNB + tid] = wsel[tid] / wsumS;
        idx_out[b * KNB + tid] = isel[tid];
    }
}

// ---------- fused gather + next-qn + bf16 emb + 3-layer MLP ----------
__global__ __launch_bounds__(256)
void gp_kernel(const float* __restrict__ vals, const int* __restrict__ idx,
               const float* __restrict__ w, const int* __restrict__ actions, int step,
               float* __restrict__ emb_out, unsigned short* __restrict__ eb_out,
               float* __restrict__ qn_out,
               const float* __restrict__ w1, const float* __restrict__ b1,
               const float* __restrict__ w2, const float* __restrict__ b2,
               const float* __restrict__ w3, const float* __restrict__ b3,
               float* __restrict__ out) {
    int b = blockIdx.x, tid = threadIdx.x;
    int a = actions[b * NSTEPS + step];
    __shared__ float wl[KNB];
    __shared__ int il[KNB];
    __shared__ float red[256];
    __shared__ float xs[DIM];
    __shared__ float h1[H1N];
    __shared__ float h2[H2N];
    if (tid < KNB) { wl[tid] = w[b * KNB + tid]; il[tid] = idx[b * KNB + tid]; }
    __syncthreads();
    const float* va = vals + (size_t)a * NMEM * DIM;
    float acc0 = 0.f, acc1 = 0.f;
    for (int k = 0; k < KNB; ++k) {
        const float* vr = va + (size_t)il[k] * DIM;
        acc0 = fmaf(wl[k], vr[tid], acc0);
        acc1 = fmaf(wl[k], vr[tid + 256], acc1);
    }
    emb_out[b * DIM + tid] = acc0;
    emb_out[b * DIM + tid + 256] = acc1;
    eb_out[b * DIM + tid] = bf16rn(acc0);
    eb_out[b * DIM + tid + 256] = bf16rn(acc1);
    xs[tid] = acc0; xs[tid + 256] = acc1;
    red[tid] = acc0 * acc0 + acc1 * acc1;
    __syncthreads();
    for (int s = 128; s > 0; s >>= 1) { if (tid < s) red[tid] += red[tid + s]; __syncthreads(); }
    if (tid == 0) qn_out[b] = red[0];
    float acc = b1[tid];
    #pragma unroll 8
    for (int d = 0; d < DIM; ++d) acc = fmaf(xs[d], w1[d * H1N + tid], acc);
    h1[tid] = acc > 0.f ? acc : expm1f(acc);
    __syncthreads();
    if (tid < H2N) {
        float a2 = b2[tid];
        #pragma unroll 8
        for (int d = 0; d < H1N; ++d) a2 = fmaf(h1[d], w2[d * H2N + tid], a2);
        h2[tid] = a2 > 0.f ? a2 : expm1f(a2);
    }
    __syncthreads();
    if (tid < 5) {
        float p = b3[tid];
        for (int d = 0; d < H2N; ++d) p = fmaf(h2[d], w3[d * 5 + tid], p);
        float o = p;
        if (tid == 1) o = 1.0f / (1.0f + expf(-p));
        out[b * (6 * 5) + (step + 1) * 5 + tid] = o;
    }
}

// ---------- standalone MLP for step 0 ----------
__global__ __launch_bounds__(256)
void predict_kernel(const float* __restrict__ emb, const float* __restrict__ w1,
                    const float* __restrict__ b1, const float* __restrict__ w2,
                    const float* __restrict__ b2, const float* __restrict__ w3,
                    const float* __restrict__ b3, float* __restrict__ out, int step) {
    int b = blockIdx.x, tid = threadIdx.x;
    __shared__ float xs[DIM];
    __shared__ float h1[H1N];
    __shared__ float h2[H2N];
    xs[tid] = emb[(size_t)b * DIM + tid];
    xs[tid + 256] = emb[(size_t)b * DIM + tid + 256];
    __syncthreads();
    float acc = b1[tid];
    #pragma unroll 8
    for (int d = 0; d < DIM; ++d) acc = fmaf(xs[d], w1[d * H1N + tid], acc);
    h1[tid] = acc > 0.f ? acc : expm1f(acc);
    __syncthreads();
    if (tid < H2N) {
        float a2 = b2[tid];
        #pragma unroll 8
        for (int d = 0; d < H1N; ++d) a2 = fmaf(h1[d], w2[d * H2N + tid], a2);
        h2[tid] = a2 > 0.f ? a2 : expm1f(a2);
    }
    __syncthreads();
    if (tid < 5) {
        float p = b3[tid];
        for (int d = 0; d < H2N; ++d) p = fmaf(h2[d], w3[d * 5 + tid], p);
        float o = p;
        if (tid == 1) o = 1.0f / (1.0f + expf(-p));
        out[b * (6 * 5) + step * 5 + tid] = o;
    }
}

extern "C" void kernel_launch(void* const* d_in, const int* in_sizes, int n_in,
                              void* d_out, int out_size, void* d_ws, size_t ws_size,
                              hipStream_t stream) {
    const float* x        = (const float*)d_in[0];
    const int*   actions  = (const int*)d_in[1];
    const float* mem_keys = (const float*)d_in[2];
    const float* mem_vals = (const float*)d_in[3];
    const float* w1 = (const float*)d_in[4];
    const float* b1 = (const float*)d_in[5];
    const float* w2 = (const float*)d_in[6];
    const float* b2 = (const float*)d_in[7];
    const float* w3 = (const float*)d_in[8];
    const float* b3 = (const float*)d_in[9];
    float* out = (float*)d_out;

    // workspace layout (bytes; 16B-aligned blocks)
    char* W = (char*)d_ws;
    unsigned short* kb    = (unsigned short*)W;                 // 76,800,000
    unsigned short* distb = (unsigned short*)(W + 76800000);    // 12,800,000
    unsigned short* eb    = (unsigned short*)(W + 89600000);    //    262,144
    float* kn   = (float*)(W + 89862144);                       //    300,032
    float* qnb  = (float*)(W + 90162176);                       //      1,024
    float* emb  = (float*)(W + 90163200);                       //    524,288
    int*   perm = (int*)(W + 90687488);                         //     15,360
    int*   cntb = (int*)(W + 90702848);                         //        128
    int*   idxb = (int*)(W + 90702976);                         //     51,200
    float* wb   = (float*)(W + 90754176);                       //     51,200
    float* psum = (float*)(W + 90805376);                       //    802,816
    float* psq  = (float*)(W + 91608192);                       //    802,816
    float* Tb   = (float*)(W + 92411008);                       //      1,024
    float* sdb  = (float*)(W + 92412032);                       //      1,024  (end ~92.4 MB)

    prep_keys_kernel<<<dim3((NACT * NMEM + 3) / 4), dim3(256), 0, stream>>>(mem_keys, kb, kn, NACT * NMEM);
    prep_x_kernel<<<dim3((BATCH + 3) / 4), dim3(256), 0, stream>>>(x, eb, qnb, BATCH);
    predict_kernel<<<dim3(BATCH), dim3(256), 0, stream>>>(x, w1, b1, w2, b2, w3, b3, out, 0);
    group_all_kernel<<<dim3(NSTEPS), dim3(256), 0, stream>>>(actions, perm, cntb);

    const float* cur = x;
    for (int j = 0; j < NSTEPS; ++j) {
        dist_kernel<<<dim3(NACT, NYT), dim3(256), 0, stream>>>(
            eb, kb, kn, perm + j * NACT * BATCH, cntb + j * 4, distb, psum, psq);
        thresh_kernel<<<dim3(BATCH / 4), dim3(256), 0, stream>>>(psum, psq, Tb, sdb);
        select_kernel<<<dim3(BATCH), dim3(1024), 0, stream>>>(
            distb, cur, mem_keys, kn, qnb, Tb, sdb, actions, j, idxb, wb);
        gp_kernel<<<dim3(BATCH), dim3(256), 0, stream>>>(
            mem_vals, idxb, wb, actions, j, emb, eb, qnb, w1, b1, w2, b2, w3, b3, out);
        cur = emb;
    }
}

// Round 11
// 626.934 us; speedup vs baseline: 1.5588x; 1.1489x over previous
//
#include <hip/hip_runtime.h>

#define BATCH 256
#define DIM 512
#define NACT 3
#define NMEM 25000
#define KNB 50
#define H1N 256
#define H2N 128
#define NSTEPS 5
#define KDELTA 0.001f

#define TB 128
#define TN 64
#define BK 64
#define NYT ((NMEM + TN - 1) / TN)   // 391 n-tiles

#define CAP 2048           // candidate buffer cap

typedef __attribute__((ext_vector_type(8))) short short8;
typedef __attribute__((ext_vector_type(4))) float f32x4;

__device__ __forceinline__ unsigned short bf16rn(float f) {
    unsigned u = __float_as_uint(f);
    u += 0x7FFFu + ((u >> 16) & 1u);
    return (unsigned short)(u >> 16);
}
__device__ __forceinline__ float blo(unsigned u) { return __uint_as_float(u << 16); }
__device__ __forceinline__ float bhi(unsigned u) { return __uint_as_float(u & 0xFFFF0000u); }

// ---------- prep keys: f32 -> bf16 copy + row norms (one wave per row) ----------
__global__ __launch_bounds__(256)
void prep_keys_kernel(const float* __restrict__ rows, unsigned short* __restrict__ kb,
                      float* __restrict__ kn, int nrows) {
    int wave = threadIdx.x >> 6, lane = threadIdx.x & 63;
    int r = blockIdx.x * 4 + wave;
    if (r >= nrows) return;
    const float* p = rows + (size_t)r * DIM;
    float4 v0 = *(const float4*)(p + lane * 8);
    float4 v1 = *(const float4*)(p + lane * 8 + 4);
    float f[8] = {v0.x, v0.y, v0.z, v0.w, v1.x, v1.y, v1.z, v1.w};
    short8 hv;
    float s = 0.f;
    #pragma unroll
    for (int i = 0; i < 8; ++i) { hv[i] = (short)bf16rn(f[i]); s += f[i] * f[i]; }
    *(short8*)(kb + (size_t)r * DIM + lane * 8) = hv;
    for (int off = 32; off; off >>= 1) s += __shfl_down(s, off);
    if (lane == 0) kn[r] = s;
}

// ---------- prep x: bf16 copy + qn ----------
__global__ __launch_bounds__(256)
void prep_x_kernel(const float* __restrict__ rows, unsigned short* __restrict__ eb,
                   float* __restrict__ qn, int nrows) {
    int wave = threadIdx.x >> 6, lane = threadIdx.x & 63;
    int r = blockIdx.x * 4 + wave;
    if (r >= nrows) return;
    const float* p = rows + (size_t)r * DIM;
    float4 v0 = *(const float4*)(p + lane * 8);
    float4 v1 = *(const float4*)(p + lane * 8 + 4);
    float f[8] = {v0.x, v0.y, v0.z, v0.w, v1.x, v1.y, v1.z, v1.w};
    short8 hv;
    float s = 0.f;
    #pragma unroll
    for (int i = 0; i < 8; ++i) { hv[i] = (short)bf16rn(f[i]); s += f[i] * f[i]; }
    *(short8*)(eb + (size_t)r * DIM + lane * 8) = hv;
    for (int off = 32; off; off >>= 1) s += __shfl_down(s, off);
    if (lane == 0) qn[r] = s;
}

// ---------- group batch rows by action, all steps in one launch ----------
__global__ __launch_bounds__(256)
void group_all_kernel(const int* __restrict__ actions,
                      int* __restrict__ perm, int* __restrict__ cnt) {
    int step = blockIdx.x;
    __shared__ int lcnt[NACT];
    __shared__ int lperm[NACT * BATCH];
    int tid = threadIdx.x;
    if (tid < NACT) lcnt[tid] = 0;
    __syncthreads();
    int a = actions[tid * NSTEPS + step];
    int pos = atomicAdd(&lcnt[a], 1);
    lperm[a * BATCH + pos] = tid;
    __syncthreads();
    if (tid < NACT) cnt[step * 4 + tid] = lcnt[tid];
    for (int aa = 0; aa < NACT; ++aa) {
        int c = lcnt[aa];
        int f = (c > 0) ? lperm[aa * BATCH] : 0;
        for (int i = c + tid; i < BATCH; i += 256) lperm[aa * BATCH + i] = f;
    }
    __syncthreads();
    for (int i = tid; i < NACT * BATCH; i += 256)
        perm[step * NACT * BATCH + i] = lperm[i];
}

// ---------- approx distance GEMM: bf16 MFMA, bf16 keys, dbuf LDS, async-stage ----------
__global__ __launch_bounds__(256)
void dist_kernel(const unsigned short* __restrict__ eb, const unsigned short* __restrict__ kb,
                 const float* __restrict__ kn, const int* __restrict__ perm,
                 const int* __restrict__ cnt, unsigned short* __restrict__ dist,
                 float* __restrict__ psum, float* __restrict__ psq) {
    int a = blockIdx.x;
    int c = cnt[a];
    int n0 = blockIdx.y * TN;

    __shared__ __align__(16) unsigned short Qh[2][TB][BK];
    __shared__ __align__(16) unsigned short Kh[2][TN][BK];
    __shared__ int rows[TB];

    int tid = threadIdx.x;
    int lane = tid & 63, wave = tid >> 6;
    int wm = wave >> 1, wn = wave & 1;

    const int qr = tid >> 1, qc = (tid & 1) * 32, qswz = (qr & 7) * 8;
    const int kr = tid >> 2, kc = (tid & 3) * 16, kswz = (kr & 7) * 8;
    int krow = (n0 + kr < NMEM) ? (n0 + kr) : (NMEM - 1);
    const unsigned short* ksrc = kb + ((size_t)a * NMEM + krow) * DIM + kc;

    int nn[2]; float knv[2]; bool nvalid[2];
    #pragma unroll
    for (int nf = 0; nf < 2; ++nf) {
        nn[nf] = n0 + wn * 32 + nf * 16 + (lane & 15);
        nvalid[nf] = nn[nf] < NMEM;
        knv[nf] = nvalid[nf] ? kn[a * NMEM + nn[nf]] : 0.f;
    }
    int slot = (blockIdx.y * 2 + wn) * BATCH;

    for (int tb0 = 0; tb0 < c; tb0 += TB) {
        __syncthreads();
        if (tid < TB) {
            int i = tb0 + tid;
            rows[tid] = perm[a * BATCH + (i < c ? i : 0)];
        }
        __syncthreads();

        const unsigned short* qsrc = eb + (size_t)rows[qr] * DIM + qc;
        f32x4 acc[4][2] = {};
        short8 qv[4], kv[2];

        // prologue: load + write chunk 0
        #pragma unroll
        for (int j = 0; j < 4; ++j) qv[j] = *(const short8*)(qsrc + j * 8);
        kv[0] = *(const short8*)(ksrc);
        kv[1] = *(const short8*)(ksrc + 8);
        #pragma unroll
        for (int j = 0; j < 4; ++j) *(short8*)&Qh[0][qr][(qc + j * 8) ^ qswz] = qv[j];
        *(short8*)&Kh[0][kr][(kc + 0) ^ kswz] = kv[0];
        *(short8*)&Kh[0][kr][(kc + 8) ^ kswz] = kv[1];
        __syncthreads();

        int cur = 0;
        for (int it = 0; it < DIM / BK; ++it) {
            if (it < DIM / BK - 1) {
                int d0 = (it + 1) * BK;
                #pragma unroll
                for (int j = 0; j < 4; ++j) qv[j] = *(const short8*)(qsrc + d0 + j * 8);
                kv[0] = *(const short8*)(ksrc + d0);
                kv[1] = *(const short8*)(ksrc + d0 + 8);
            }
            #pragma unroll
            for (int kk = 0; kk < BK; kk += 32) {
                int kcol = kk + (lane >> 4) * 8;
                short8 av[4], bv[2];
                #pragma unroll
                for (int mf = 0; mf < 4; ++mf) {
                    int m = wm * 64 + mf * 16 + (lane & 15);
                    av[mf] = *(const short8*)&Qh[cur][m][kcol ^ ((m & 7) * 8)];
                }
                #pragma unroll
                for (int nf = 0; nf < 2; ++nf) {
                    int n = wn * 32 + nf * 16 + (lane & 15);
                    bv[nf] = *(const short8*)&Kh[cur][n][kcol ^ ((n & 7) * 8)];
                }
                #pragma unroll
                for (int mf = 0; mf < 4; ++mf)
                    #pragma unroll
                    for (int nf = 0; nf < 2; ++nf)
                        acc[mf][nf] = __builtin_amdgcn_mfma_f32_16x16x32_bf16(av[mf], bv[nf], acc[mf][nf], 0, 0, 0);
            }
            if (it < DIM / BK - 1) {
                #pragma unroll
                for (int j = 0; j < 4; ++j) *(short8*)&Qh[cur ^ 1][qr][(qc + j * 8) ^ qswz] = qv[j];
                *(short8*)&Kh[cur ^ 1][kr][(kc + 0) ^ kswz] = kv[0];
                *(short8*)&Kh[cur ^ 1][kr][(kc + 8) ^ kswz] = kv[1];
                __syncthreads();
            }
            cur ^= 1;
        }

        // ---- epilogue: store bf16 dist + per-row stats partials ----
        #pragma unroll
        for (int mf = 0; mf < 4; ++mf) {
            #pragma unroll
            for (int r = 0; r < 4; ++r) {
                int m = wm * 64 + mf * 16 + (lane >> 4) * 4 + r;
                int b = rows[m];
                float s = 0.f, q2 = 0.f;
                #pragma unroll
                for (int nf = 0; nf < 2; ++nf) {
                    if (nvalid[nf]) {
                        float d = knv[nf] - 2.0f * acc[mf][nf][r];
                        dist[(size_t)b * NMEM + nn[nf]] = bf16rn(d);
                        s += d; q2 += d * d;
                    }
                }
                #pragma unroll
                for (int x = 1; x < 16; x <<= 1) { s += __shfl_xor(s, x); q2 += __shfl_xor(q2, x); }
                if ((lane & 15) == 0) { psum[slot + b] = s; psq[slot + b] = q2; }
            }
        }
    }
}

// ---------- select: fused stats -> candidate collect -> exact f32 refine -> top-50 ----------
__global__ __launch_bounds__(1024)
void select_kernel(const unsigned short* __restrict__ dist, const float* __restrict__ emb,
                   const float* __restrict__ keys, const float* __restrict__ kn,
                   const float* __restrict__ qn,
                   const float* __restrict__ psum, const float* __restrict__ psq,
                   const int* __restrict__ actions,
                   int step, int* __restrict__ idx_out, float* __restrict__ w_out) {
    __shared__ float qs[DIM];
    __shared__ float wsum16[16], wsq16[16];
    __shared__ float Tsh, sdsh;
    __shared__ unsigned cntS;
    __shared__ int candb[CAP];
    __shared__ float dex[CAP];
    __shared__ float wsel[KNB];
    __shared__ int   isel[KNB];
    __shared__ float wsumS;

    int b = blockIdx.x, tid = threadIdx.x;
    int lane = tid & 63, wid = tid >> 6;
    const uint4* d8 = (const uint4*)(dist + (size_t)b * NMEM);   // 8 bf16 per uint4

    if (tid < 128) *(float4*)&qs[tid * 4] = *(const float4*)(emb + (size_t)b * DIM + tid * 4);

    // ---- phase 0: stats from dist partials (fused old thresh_kernel) ----
    {
        float s = 0.f, q = 0.f;
        for (int i = tid; i < NYT * 2; i += 1024) {
            s += psum[i * BATCH + b];
            q += psq[i * BATCH + b];
        }
        #pragma unroll
        for (int m = 32; m; m >>= 1) { s += __shfl_xor(s, m); q += __shfl_xor(q, m); }
        if (lane == 0) { wsum16[wid] = s; wsq16[wid] = q; }
    }
    __syncthreads();
    if (tid == 0) {
        float S = 0.f, Q = 0.f;
        for (int i = 0; i < 16; ++i) { S += wsum16[i]; Q += wsq16[i]; }
        float mean = S / (float)NMEM;
        float var = Q / (float)NMEM - mean * mean;
        float sd = sqrtf(fmaxf(var, 0.f));
        sdsh = sd;
        Tsh = mean - 2.575f * sd;
    }
    __syncthreads();

    // ---- phase 1: collect all d < T (widen if under 128) ----
    float T = Tsh, sd = sdsh;
    for (int it = 0; it < 8; ++it) {
        if (tid == 0) cntS = 0;
        __syncthreads();
        for (int i = tid; i < NMEM / 8; i += 1024) {
            uint4 v = d8[i];
            int n = i * 8;
            float f[8] = {blo(v.x), bhi(v.x), blo(v.y), bhi(v.y),
                          blo(v.z), bhi(v.z), blo(v.w), bhi(v.w)};
            #pragma unroll
            for (int k = 0; k < 8; ++k)
                if (f[k] < T) { unsigned p = atomicAdd(&cntS, 1u); if (p < CAP) candb[p] = n + k; }
        }
        __syncthreads();
        if (cntS >= 128) break;
        T += 0.6f * sd;
        __syncthreads();
    }
    int C = (int)cntS; if (C > CAP) C = CAP;

    // ---- phase 2: exact f32 distances (8 threads/cand, interleaved dims: conflict-free) ----
    int a = actions[b * NSTEPS + step];
    float qnb = qn[b];
    const float* keysA = keys + (size_t)a * NMEM * DIM;
    int cslot = tid >> 3, sub = tid & 7;
    int sweeps = (C + 127) >> 7;
    for (int sw = 0; sw < sweeps; ++sw) {
        int ci = (sw << 7) + cslot;
        float dot = 0.f;
        int n = 0;
        if (ci < C) {
            n = candb[ci];
            const float* kr = keysA + (size_t)n * DIM;
            #pragma unroll
            for (int k = 0; k < 16; ++k) {
                int o = sub * 4 + k * 32;
                float4 kv = *(const float4*)(kr + o);
                dot = fmaf(kv.x, qs[o+0], dot);
                dot = fmaf(kv.y, qs[o+1], dot);
                dot = fmaf(kv.z, qs[o+2], dot);
                dot = fmaf(kv.w, qs[o+3], dot);
            }
        }
        dot += __shfl_xor(dot, 1);
        dot += __shfl_xor(dot, 2);
        dot += __shfl_xor(dot, 4);
        if (ci < C && sub == 0)
            dex[ci] = qnb + kn[a * NMEM + n] - 2.0f * dot;
    }
    __syncthreads();

    // ---- phase 3: exact (d, idx) rank; top-50 ----
    for (int ci = tid; ci < C; ci += 1024) {
        float di = dex[ci]; int ni = candb[ci];
        int rank = 0;
        for (int j = 0; j < C; ++j) {
            float dj = dex[j];
            rank += (dj < di || (dj == di && candb[j] < ni)) ? 1 : 0;
        }
        if (rank < KNB) { wsel[rank] = 1.0f / (di + KDELTA); isel[rank] = ni; }
    }
    __syncthreads();
    if (tid == 0) {
        float ssum = 0.f;
        for (int i = 0; i < KNB; ++i) ssum += wsel[i];
        wsumS = ssum;
    }
    __syncthreads();
    if (tid < KNB) {
        w_out[b * KNB + tid] = wsel[tid] / wsumS;
        idx_out[b * KNB + tid] = isel[tid];
    }
}

// ---------- fused gather + next-qn + bf16 emb + 3-layer MLP (512 threads) ----------
__global__ __launch_bounds__(512)
void gp_kernel(const float* __restrict__ vals, const int* __restrict__ idx,
               const float* __restrict__ w, const int* __restrict__ actions, int step,
               float* __restrict__ emb_out, unsigned short* __restrict__ eb_out,
               float* __restrict__ qn_out,
               const float* __restrict__ w1, const float* __restrict__ b1,
               const float* __restrict__ w2, const float* __restrict__ b2,
               const float* __restrict__ w3, const float* __restrict__ b3,
               float* __restrict__ out) {
    int b = blockIdx.x, tid = threadIdx.x;
    int a = actions[b * NSTEPS + step];
    __shared__ float wl[KNB];
    __shared__ int il[KNB];
    __shared__ float red[512];
    __shared__ float xs[DIM];
    __shared__ float part[512];
    __shared__ float h1[H1N];
    __shared__ float h2[H2N];
    if (tid < KNB) { wl[tid] = w[b * KNB + tid]; il[tid] = idx[b * KNB + tid]; }
    __syncthreads();
    // gather: thread tid owns dim tid (coalesced across 512 threads)
    const float* va = vals + (size_t)a * NMEM * DIM + tid;
    float acc = 0.f;
    #pragma unroll 10
    for (int k = 0; k < KNB; ++k)
        acc = fmaf(wl[k], va[(size_t)il[k] * DIM], acc);
    emb_out[b * DIM + tid] = acc;
    eb_out[b * DIM + tid] = bf16rn(acc);
    xs[tid] = acc;
    red[tid] = acc * acc;
    __syncthreads();
    for (int s = 256; s > 0; s >>= 1) { if (tid < s) red[tid] += red[tid + s]; __syncthreads(); }
    if (tid == 0) qn_out[b] = red[0];
    // ---- MLP layer 1: 256 outputs, split-K over 2 halves ----
    {
        int o = tid & (H1N - 1), half = tid >> 8;
        const float* wc = w1 + (size_t)half * 256 * H1N + o;
        const float* xc = xs + half * 256;
        float s = 0.f;
        #pragma unroll 8
        for (int d = 0; d < 256; ++d) s = fmaf(xc[d], wc[(size_t)d * H1N], s);
        part[tid] = s;
    }
    __syncthreads();
    if (tid < H1N) {
        float v = part[tid] + part[tid + H1N] + b1[tid];
        h1[tid] = v > 0.f ? v : expm1f(v);
    }
    __syncthreads();
    // ---- MLP layer 2: 128 outputs, split-K over 4 quarters ----
    {
        int o = tid & (H2N - 1), q = tid >> 7;
        const float* wc = w2 + (size_t)q * 64 * H2N + o;
        const float* hc = h1 + q * 64;
        float s = 0.f;
        #pragma unroll 8
        for (int d = 0; d < 64; ++d) s = fmaf(hc[d], wc[(size_t)d * H2N], s);
        part[tid] = s;
    }
    __syncthreads();
    if (tid < H2N) {
        float v = part[tid] + part[tid + H2N] + part[tid + 2 * H2N] + part[tid + 3 * H2N] + b2[tid];
        h2[tid] = v > 0.f ? v : expm1f(v);
    }
    __syncthreads();
    if (tid < 5) {
        float p = b3[tid];
        for (int d = 0; d < H2N; ++d) p = fmaf(h2[d], w3[d * 5 + tid], p);
        float o = p;
        if (tid == 1) o = 1.0f / (1.0f + expf(-p));
        out[b * (6 * 5) + (step + 1) * 5 + tid] = o;
    }
}

// ---------- standalone MLP for step 0 ----------
__global__ __launch_bounds__(256)
void predict_kernel(const float* __restrict__ emb, const float* __restrict__ w1,
                    const float* __restrict__ b1, const float* __restrict__ w2,
                    const float* __restrict__ b2, const float* __restrict__ w3,
                    const float* __restrict__ b3, float* __restrict__ out, int step) {
    int b = blockIdx.x, tid = threadIdx.x;
    __shared__ float xs[DIM];
    __shared__ float h1[H1N];
    __shared__ float h2[H2N];
    xs[tid] = emb[(size_t)b * DIM + tid];
    xs[tid + 256] = emb[(size_t)b * DIM + tid + 256];
    __syncthreads();
    float acc = b1[tid];
    #pragma unroll 8
    for (int d = 0; d < DIM; ++d) acc = fmaf(xs[d], w1[d * H1N + tid], acc);
    h1[tid] = acc > 0.f ? acc : expm1f(acc);
    __syncthreads();
    if (tid < H2N) {
        float a2 = b2[tid];
        #pragma unroll 8
        for (int d = 0; d < H1N; ++d) a2 = fmaf(h1[d], w2[d * H2N + tid], a2);
        h2[tid] = a2 > 0.f ? a2 : expm1f(a2);
    }
    __syncthreads();
    if (tid < 5) {
        float p = b3[tid];
        for (int d = 0; d < H2N; ++d) p = fmaf(h2[d], w3[d * 5 + tid], p);
        float o = p;
        if (tid == 1) o = 1.0f / (1.0f + expf(-p));
        out[b * (6 * 5) + step * 5 + tid] = o;
    }
}

extern "C" void kernel_launch(void* const* d_in, const int* in_sizes, int n_in,
                              void* d_out, int out_size, void* d_ws, size_t ws_size,
                              hipStream_t stream) {
    const float* x        = (const float*)d_in[0];
    const int*   actions  = (const int*)d_in[1];
    const float* mem_keys = (const float*)d_in[2];
    const float* mem_vals = (const float*)d_in[3];
    const float* w1 = (const float*)d_in[4];
    const float* b1 = (const float*)d_in[5];
    const float* w2 = (const float*)d_in[6];
    const float* b2 = (const float*)d_in[7];
    const float* w3 = (const float*)d_in[8];
    const float* b3 = (const float*)d_in[9];
    float* out = (float*)d_out;

    // workspace layout (bytes; 16B-aligned blocks)
    char* W = (char*)d_ws;
    unsigned short* kb    = (unsigned short*)W;                 // 76,800,000
    unsigned short* distb = (unsigned short*)(W + 76800000);    // 12,800,000
    unsigned short* eb    = (unsigned short*)(W + 89600000);    //    262,144
    float* kn   = (float*)(W + 89862144);                       //    300,032
    float* qnb  = (float*)(W + 90162176);                       //      1,024
    float* emb  = (float*)(W + 90163200);                       //    524,288
    int*   perm = (int*)(W + 90687488);                         //     15,360
    int*   cntb = (int*)(W + 90702848);                         //        128
    int*   idxb = (int*)(W + 90702976);                         //     51,200
    float* wb   = (float*)(W + 90754176);                       //     51,200
    float* psum = (float*)(W + 90805376);                       //    802,816
    float* psq  = (float*)(W + 91608192);                       //    802,816  (end ~92.4 MB)

    prep_keys_kernel<<<dim3((NACT * NMEM + 3) / 4), dim3(256), 0, stream>>>(mem_keys, kb, kn, NACT * NMEM);
    prep_x_kernel<<<dim3((BATCH + 3) / 4), dim3(256), 0, stream>>>(x, eb, qnb, BATCH);
    predict_kernel<<<dim3(BATCH), dim3(256), 0, stream>>>(x, w1, b1, w2, b2, w3, b3, out, 0);
    group_all_kernel<<<dim3(NSTEPS), dim3(256), 0, stream>>>(actions, perm, cntb);

    const float* cur = x;
    for (int j = 0; j < NSTEPS; ++j) {
        dist_kernel<<<dim3(NACT, NYT), dim3(256), 0, stream>>>(
            eb, kb, kn, perm + j * NACT * BATCH, cntb + j * 4, distb, psum, psq);
        select_kernel<<<dim3(BATCH), dim3(1024), 0, stream>>>(
            distb, cur, mem_keys, kn, qnb, psum, psq, actions, j, idxb, wb);
        gp_kernel<<<dim3(BATCH), dim3(512), 0, stream>>>(
            mem_vals, idxb, wb, actions, j, emb, eb, qnb, w1, b1, w2, b2, w3, b3, out);
        cur = emb;
    }
}

// Round 12
// 614.831 us; speedup vs baseline: 1.5895x; 1.0197x over previous
//
#include <hip/hip_runtime.h>

#define BATCH 256
#define DIM 512
#define NACT 3
#define NMEM 25000
#define KNB 50
#define H1N 256
#define H2N 128
#define NSTEPS 5
#define KDELTA 0.001f

#define TB 128
#define TN 64
#define BK 64
#define NCH (DIM / BK)               // 8 k-chunks
#define NYT ((NMEM + TN - 1) / TN)   // 391 n-tiles

#define CAP 2048           // candidate buffer cap

typedef __attribute__((ext_vector_type(8))) short short8;
typedef __attribute__((ext_vector_type(4))) float f32x4;

__device__ __forceinline__ unsigned short bf16rn(float f) {
    unsigned u = __float_as_uint(f);
    u += 0x7FFFu + ((u >> 16) & 1u);
    return (unsigned short)(u >> 16);
}
__device__ __forceinline__ float blo(unsigned u) { return __uint_as_float(u << 16); }
__device__ __forceinline__ float bhi(unsigned u) { return __uint_as_float(u & 0xFFFF0000u); }

// ---------- prep keys: f32 -> bf16 copy + row norms (one wave per row) ----------
__global__ __launch_bounds__(256)
void prep_keys_kernel(const float* __restrict__ rows, unsigned short* __restrict__ kb,
                      float* __restrict__ kn, int nrows) {
    int wave = threadIdx.x >> 6, lane = threadIdx.x & 63;
    int r = blockIdx.x * 4 + wave;
    if (r >= nrows) return;
    const float* p = rows + (size_t)r * DIM;
    float4 v0 = *(const float4*)(p + lane * 8);
    float4 v1 = *(const float4*)(p + lane * 8 + 4);
    float f[8] = {v0.x, v0.y, v0.z, v0.w, v1.x, v1.y, v1.z, v1.w};
    short8 hv;
    float s = 0.f;
    #pragma unroll
    for (int i = 0; i < 8; ++i) { hv[i] = (short)bf16rn(f[i]); s += f[i] * f[i]; }
    *(short8*)(kb + (size_t)r * DIM + lane * 8) = hv;
    for (int off = 32; off; off >>= 1) s += __shfl_down(s, off);
    if (lane == 0) kn[r] = s;
}

// ---------- prep x: bf16 copy + qn ----------
__global__ __launch_bounds__(256)
void prep_x_kernel(const float* __restrict__ rows, unsigned short* __restrict__ eb,
                   float* __restrict__ qn, int nrows) {
    int wave = threadIdx.x >> 6, lane = threadIdx.x & 63;
    int r = blockIdx.x * 4 + wave;
    if (r >= nrows) return;
    const float* p = rows + (size_t)r * DIM;
    float4 v0 = *(const float4*)(p + lane * 8);
    float4 v1 = *(const float4*)(p + lane * 8 + 4);
    float f[8] = {v0.x, v0.y, v0.z, v0.w, v1.x, v1.y, v1.z, v1.w};
    short8 hv;
    float s = 0.f;
    #pragma unroll
    for (int i = 0; i < 8; ++i) { hv[i] = (short)bf16rn(f[i]); s += f[i] * f[i]; }
    *(short8*)(eb + (size_t)r * DIM + lane * 8) = hv;
    for (int off = 32; off; off >>= 1) s += __shfl_down(s, off);
    if (lane == 0) qn[r] = s;
}

// ---------- group batch rows by action, all steps in one launch ----------
__global__ __launch_bounds__(256)
void group_all_kernel(const int* __restrict__ actions,
                      int* __restrict__ perm, int* __restrict__ cnt) {
    int step = blockIdx.x;
    __shared__ int lcnt[NACT];
    __shared__ int lperm[NACT * BATCH];
    int tid = threadIdx.x;
    if (tid < NACT) lcnt[tid] = 0;
    __syncthreads();
    int a = actions[tid * NSTEPS + step];
    int pos = atomicAdd(&lcnt[a], 1);
    lperm[a * BATCH + pos] = tid;
    __syncthreads();
    if (tid < NACT) cnt[step * 4 + tid] = lcnt[tid];
    for (int aa = 0; aa < NACT; ++aa) {
        int c = lcnt[aa];
        int f = (c > 0) ? lperm[aa * BATCH] : 0;
        for (int i = c + tid; i < BATCH; i += 256) lperm[aa * BATCH + i] = f;
    }
    __syncthreads();
    for (int i = tid; i < NACT * BATCH; i += 256)
        perm[step * NACT * BATCH + i] = lperm[i];
}

// ---------- approx distance GEMM: bf16 MFMA, 2-deep reg prefetch, dbuf LDS ----------
__global__ __launch_bounds__(256)
void dist_kernel(const unsigned short* __restrict__ eb, const unsigned short* __restrict__ kb,
                 const float* __restrict__ kn, const int* __restrict__ perm,
                 const int* __restrict__ cnt, unsigned short* __restrict__ dist,
                 float* __restrict__ psum, float* __restrict__ psq) {
    int a = blockIdx.x;
    int c = cnt[a];
    int n0 = blockIdx.y * TN;

    __shared__ __align__(16) unsigned short Qh[2][TB][BK];
    __shared__ __align__(16) unsigned short Kh[2][TN][BK];
    __shared__ int rows[TB];

    int tid = threadIdx.x;
    int lane = tid & 63, wave = tid >> 6;
    int wm = wave >> 1, wn = wave & 1;

    const int qr = tid >> 1, qc = (tid & 1) * 32, qswz = (qr & 7) * 8;
    const int kr = tid >> 2, kc = (tid & 3) * 16, kswz = (kr & 7) * 8;
    int krow = (n0 + kr < NMEM) ? (n0 + kr) : (NMEM - 1);
    const unsigned short* ksrc = kb + ((size_t)a * NMEM + krow) * DIM + kc;

    int nn[2]; float knv[2]; bool nvalid[2];
    #pragma unroll
    for (int nf = 0; nf < 2; ++nf) {
        nn[nf] = n0 + wn * 32 + nf * 16 + (lane & 15);
        nvalid[nf] = nn[nf] < NMEM;
        knv[nf] = nvalid[nf] ? kn[a * NMEM + nn[nf]] : 0.f;
    }
    int slot = (blockIdx.y * 2 + wn) * BATCH;

    for (int tb0 = 0; tb0 < c; tb0 += TB) {
        __syncthreads();
        if (tid < TB) {
            int i = tb0 + tid;
            rows[tid] = perm[a * BATCH + (i < c ? i : 0)];
        }
        __syncthreads();

        const unsigned short* qsrc = eb + (size_t)rows[qr] * DIM + qc;
        f32x4 acc[4][2] = {};
        short8 qA[4], qB[4], kA[2], kB[2];

        // prologue: issue chunk0 -> A, chunk1 -> B (both in flight), write buf0 from A
        #pragma unroll
        for (int j = 0; j < 4; ++j) qA[j] = *(const short8*)(qsrc + j * 8);
        kA[0] = *(const short8*)(ksrc);
        kA[1] = *(const short8*)(ksrc + 8);
        #pragma unroll
        for (int j = 0; j < 4; ++j) qB[j] = *(const short8*)(qsrc + BK + j * 8);
        kB[0] = *(const short8*)(ksrc + BK);
        kB[1] = *(const short8*)(ksrc + BK + 8);
        #pragma unroll
        for (int j = 0; j < 4; ++j) *(short8*)&Qh[0][qr][(qc + j * 8) ^ qswz] = qA[j];
        *(short8*)&Kh[0][kr][(kc + 0) ^ kswz] = kA[0];
        *(short8*)&Kh[0][kr][(kc + 8) ^ kswz] = kA[1];
        __syncthreads();

        auto mfma_phase = [&](int B) {
            #pragma unroll
            for (int kk = 0; kk < BK; kk += 32) {
                int kcol = kk + (lane >> 4) * 8;
                short8 av[4], bv[2];
                #pragma unroll
                for (int mf = 0; mf < 4; ++mf) {
                    int m = wm * 64 + mf * 16 + (lane & 15);
                    av[mf] = *(const short8*)&Qh[B][m][kcol ^ ((m & 7) * 8)];
                }
                #pragma unroll
                for (int nf = 0; nf < 2; ++nf) {
                    int n = wn * 32 + nf * 16 + (lane & 15);
                    bv[nf] = *(const short8*)&Kh[B][n][kcol ^ ((n & 7) * 8)];
                }
                #pragma unroll
                for (int mf = 0; mf < 4; ++mf)
                    #pragma unroll
                    for (int nf = 0; nf < 2; ++nf)
                        acc[mf][nf] = __builtin_amdgcn_mfma_f32_16x16x32_bf16(av[mf], bv[nf], acc[mf][nf], 0, 0, 0);
            }
        };

        #pragma unroll
        for (int p = 0; p < NCH / 2; ++p) {
            const int it = 2 * p;
            // A-half: prefetch chunk it+2 into A (free), compute buf0 (chunk it)
            if (it + 2 < NCH) {
                const int d0 = (it + 2) * BK;
                #pragma unroll
                for (int j = 0; j < 4; ++j) qA[j] = *(const short8*)(qsrc + d0 + j * 8);
                kA[0] = *(const short8*)(ksrc + d0);
                kA[1] = *(const short8*)(ksrc + d0 + 8);
            }
            mfma_phase(0);
            {   // write buf1 from B (chunk it+1, issued 2 phases ago)
                #pragma unroll
                for (int j = 0; j < 4; ++j) *(short8*)&Qh[1][qr][(qc + j * 8) ^ qswz] = qB[j];
                *(short8*)&Kh[1][kr][(kc + 0) ^ kswz] = kB[0];
                *(short8*)&Kh[1][kr][(kc + 8) ^ kswz] = kB[1];
                __syncthreads();
            }
            // B-half: prefetch chunk it+3 into B, compute buf1 (chunk it+1)
            if (it + 3 < NCH) {
                const int d0 = (it + 3) * BK;
                #pragma unroll
                for (int j = 0; j < 4; ++j) qB[j] = *(const short8*)(qsrc + d0 + j * 8);
                kB[0] = *(const short8*)(ksrc + d0);
                kB[1] = *(const short8*)(ksrc + d0 + 8);
            }
            mfma_phase(1);
            if (it + 2 < NCH) {   // write buf0 from A (chunk it+2)
                #pragma unroll
                for (int j = 0; j < 4; ++j) *(short8*)&Qh[0][qr][(qc + j * 8) ^ qswz] = qA[j];
                *(short8*)&Kh[0][kr][(kc + 0) ^ kswz] = kA[0];
                *(short8*)&Kh[0][kr][(kc + 8) ^ kswz] = kA[1];
                __syncthreads();
            }
        }

        // ---- epilogue: store bf16 dist + per-row stats partials ----
        #pragma unroll
        for (int mf = 0; mf < 4; ++mf) {
            #pragma unroll
            for (int r = 0; r < 4; ++r) {
                int m = wm * 64 + mf * 16 + (lane >> 4) * 4 + r;
                int b = rows[m];
                float s = 0.f, q2 = 0.f;
                #pragma unroll
                for (int nf = 0; nf < 2; ++nf) {
                    if (nvalid[nf]) {
                        float d = knv[nf] - 2.0f * acc[mf][nf][r];
                        dist[(size_t)b * NMEM + nn[nf]] = bf16rn(d);
                        s += d; q2 += d * d;
                    }
                }
                #pragma unroll
                for (int x = 1; x < 16; x <<= 1) { s += __shfl_xor(s, x); q2 += __shfl_xor(q2, x); }
                if ((lane & 15) == 0) { psum[slot + b] = s; psq[slot + b] = q2; }
            }
        }
    }
}

// ---------- select: fused stats -> candidate collect -> exact f32 refine -> top-50 ----------
__global__ __launch_bounds__(1024)
void select_kernel(const unsigned short* __restrict__ dist, const float* __restrict__ emb,
                   const float* __restrict__ keys, const float* __restrict__ kn,
                   const float* __restrict__ qn,
                   const float* __restrict__ psum, const float* __restrict__ psq,
                   const int* __restrict__ actions,
                   int step, int* __restrict__ idx_out, float* __restrict__ w_out) {
    __shared__ float qs[DIM];
    __shared__ float wsum16[16], wsq16[16];
    __shared__ float Tsh, sdsh;
    __shared__ unsigned cntS;
    __shared__ int candb[CAP];
    __shared__ float dex[CAP];
    __shared__ float wsel[KNB];
    __shared__ int   isel[KNB];
    __shared__ float wsumS;

    int b = blockIdx.x, tid = threadIdx.x;
    int lane = tid & 63, wid = tid >> 6;
    const uint4* d8 = (const uint4*)(dist + (size_t)b * NMEM);   // 8 bf16 per uint4

    if (tid < 128) *(float4*)&qs[tid * 4] = *(const float4*)(emb + (size_t)b * DIM + tid * 4);

    // ---- phase 0: stats from dist partials ----
    {
        float s = 0.f, q = 0.f;
        for (int i = tid; i < NYT * 2; i += 1024) {
            s += psum[i * BATCH + b];
            q += psq[i * BATCH + b];
        }
        #pragma unroll
        for (int m = 32; m; m >>= 1) { s += __shfl_xor(s, m); q += __shfl_xor(q, m); }
        if (lane == 0) { wsum16[wid] = s; wsq16[wid] = q; }
    }
    __syncthreads();
    if (tid == 0) {
        float S = 0.f, Q = 0.f;
        for (int i = 0; i < 16; ++i) { S += wsum16[i]; Q += wsq16[i]; }
        float mean = S / (float)NMEM;
        float var = Q / (float)NMEM - mean * mean;
        float sd = sqrtf(fmaxf(var, 0.f));
        sdsh = sd;
        Tsh = mean - 2.40f * sd;   // expected ~205 cands; P(cnt<128) ~ 3e-8 (widen ~never fires)
    }
    __syncthreads();

    // ---- phase 1: collect all d < T (widen guard kept for safety) ----
    float T = Tsh, sd = sdsh;
    for (int it = 0; it < 8; ++it) {
        if (tid == 0) cntS = 0;
        __syncthreads();
        for (int i = tid; i < NMEM / 8; i += 1024) {
            uint4 v = d8[i];
            int n = i * 8;
            float f[8] = {blo(v.x), bhi(v.x), blo(v.y), bhi(v.y),
                          blo(v.z), bhi(v.z), blo(v.w), bhi(v.w)};
            #pragma unroll
            for (int k = 0; k < 8; ++k)
                if (f[k] < T) { unsigned p = atomicAdd(&cntS, 1u); if (p < CAP) candb[p] = n + k; }
        }
        __syncthreads();
        if (cntS >= 128) break;
        T += 0.6f * sd;
        __syncthreads();
    }
    int C = (int)cntS; if (C > CAP) C = CAP;

    // ---- phase 2: exact f32 distances (8 threads/cand, interleaved dims: conflict-free) ----
    int a = actions[b * NSTEPS + step];
    float qnb = qn[b];
    const float* keysA = keys + (size_t)a * NMEM * DIM;
    int cslot = tid >> 3, sub = tid & 7;
    int sweeps = (C + 127) >> 7;
    for (int sw = 0; sw < sweeps; ++sw) {
        int ci = (sw << 7) + cslot;
        float dot = 0.f;
        int n = 0;
        if (ci < C) {
            n = candb[ci];
            const float* kr = keysA + (size_t)n * DIM;
            #pragma unroll
            for (int k = 0; k < 16; ++k) {
                int o = sub * 4 + k * 32;
                float4 kv = *(const float4*)(kr + o);
                dot = fmaf(kv.x, qs[o+0], dot);
                dot = fmaf(kv.y, qs[o+1], dot);
                dot = fmaf(kv.z, qs[o+2], dot);
                dot = fmaf(kv.w, qs[o+3], dot);
            }
        }
        dot += __shfl_xor(dot, 1);
        dot += __shfl_xor(dot, 2);
        dot += __shfl_xor(dot, 4);
        if (ci < C && sub == 0)
            dex[ci] = qnb + kn[a * NMEM + n] - 2.0f * dot;
    }
    __syncthreads();

    // ---- phase 3: exact (d, idx) rank; top-50 ----
    for (int ci = tid; ci < C; ci += 1024) {
        float di = dex[ci]; int ni = candb[ci];
        int rank = 0;
        for (int j = 0; j < C; ++j) {
            float dj = dex[j];
            rank += (dj < di || (dj == di && candb[j] < ni)) ? 1 : 0;
        }
        if (rank < KNB) { wsel[rank] = 1.0f / (di + KDELTA); isel[rank] = ni; }
    }
    __syncthreads();
    if (tid == 0) {
        float ssum = 0.f;
        for (int i = 0; i < KNB; ++i) ssum += wsel[i];
        wsumS = ssum;
    }
    __syncthreads();
    if (tid < KNB) {
        w_out[b * KNB + tid] = wsel[tid] / wsumS;
        idx_out[b * KNB + tid] = isel[tid];
    }
}

// ---------- fused gather + next-qn + bf16 emb + 3-layer MLP (512 threads) ----------
__global__ __launch_bounds__(512)
void gp_kernel(const float* __restrict__ vals, const int* __restrict__ idx,
               const float* __restrict__ w, const int* __restrict__ actions, int step,
               float* __restrict__ emb_out, unsigned short* __restrict__ eb_out,
               float* __restrict__ qn_out,
               const float* __restrict__ w1, const float* __restrict__ b1,
               const float* __restrict__ w2, const float* __restrict__ b2,
               const float* __restrict__ w3, const float* __restrict__ b3,
               float* __restrict__ out) {
    int b = blockIdx.x, tid = threadIdx.x;
    int a = actions[b * NSTEPS + step];
    __shared__ float wl[KNB];
    __shared__ int il[KNB];
    __shared__ float red[512];
    __shared__ float xs[DIM];
    __shared__ float part[512];
    __shared__ float h1[H1N];
    __shared__ float h2[H2N];
    if (tid < KNB) { wl[tid] = w[b * KNB + tid]; il[tid] = idx[b * KNB + tid]; }
    __syncthreads();
    const float* va = vals + (size_t)a * NMEM * DIM + tid;
    float acc = 0.f;
    #pragma unroll 10
    for (int k = 0; k < KNB; ++k)
        acc = fmaf(wl[k], va[(size_t)il[k] * DIM], acc);
    emb_out[b * DIM + tid] = acc;
    eb_out[b * DIM + tid] = bf16rn(acc);
    xs[tid] = acc;
    red[tid] = acc * acc;
    __syncthreads();
    for (int s = 256; s > 0; s >>= 1) { if (tid < s) red[tid] += red[tid + s]; __syncthreads(); }
    if (tid == 0) qn_out[b] = red[0];
    {
        int o = tid & (H1N - 1), half = tid >> 8;
        const float* wc = w1 + (size_t)half * 256 * H1N + o;
        const float* xc = xs + half * 256;
        float s = 0.f;
        #pragma unroll 8
        for (int d = 0; d < 256; ++d) s = fmaf(xc[d], wc[(size_t)d * H1N], s);
        part[tid] = s;
    }
    __syncthreads();
    if (tid < H1N) {
        float v = part[tid] + part[tid + H1N] + b1[tid];
        h1[tid] = v > 0.f ? v : expm1f(v);
    }
    __syncthreads();
    {
        int o = tid & (H2N - 1), q = tid >> 7;
        const float* wc = w2 + (size_t)q * 64 * H2N + o;
        const float* hc = h1 + q * 64;
        float s = 0.f;
        #pragma unroll 8
        for (int d = 0; d < 64; ++d) s = fmaf(hc[d], wc[(size_t)d * H2N], s);
        part[tid] = s;
    }
    __syncthreads();
    if (tid < H2N) {
        float v = part[tid] + part[tid + H2N] + part[tid + 2 * H2N] + part[tid + 3 * H2N] + b2[tid];
        h2[tid] = v > 0.f ? v : expm1f(v);
    }
    __syncthreads();
    if (tid < 5) {
        float p = b3[tid];
        for (int d = 0; d < H2N; ++d) p = fmaf(h2[d], w3[d * 5 + tid], p);
        float o = p;
        if (tid == 1) o = 1.0f / (1.0f + expf(-p));
        out[b * (6 * 5) + (step + 1) * 5 + tid] = o;
    }
}

// ---------- standalone MLP for step 0 ----------
__global__ __launch_bounds__(256)
void predict_kernel(const float* __restrict__ emb, const float* __restrict__ w1,
                    const float* __restrict__ b1, const float* __restrict__ w2,
                    const float* __restrict__ b2, const float* __restrict__ w3,
                    const float* __restrict__ b3, float* __restrict__ out, int step) {
    int b = blockIdx.x, tid = threadIdx.x;
    __shared__ float xs[DIM];
    __shared__ float h1[H1N];
    __shared__ float h2[H2N];
    xs[tid] = emb[(size_t)b * DIM + tid];
    xs[tid + 256] = emb[(size_t)b * DIM + tid + 256];
    __syncthreads();
    float acc = b1[tid];
    #pragma unroll 8
    for (int d = 0; d < DIM; ++d) acc = fmaf(xs[d], w1[d * H1N + tid], acc);
    h1[tid] = acc > 0.f ? acc : expm1f(acc);
    __syncthreads();
    if (tid < H2N) {
        float a2 = b2[tid];
        #pragma unroll 8
        for (int d = 0; d < H1N; ++d) a2 = fmaf(h1[d], w2[d * H2N + tid], a2);
        h2[tid] = a2 > 0.f ? a2 : expm1f(a2);
    }
    __syncthreads();
    if (tid < 5) {
        float p = b3[tid];
        for (int d = 0; d < H2N; ++d) p = fmaf(h2[d], w3[d * 5 + tid], p);
        float o = p;
        if (tid == 1) o = 1.0f / (1.0f + expf(-p));
        out[b * (6 * 5) + step * 5 + tid] = o;
    }
}

extern "C" void kernel_launch(void* const* d_in, const int* in_sizes, int n_in,
                              void* d_out, int out_size, void* d_ws, size_t ws_size,
                              hipStream_t stream) {
    const float* x        = (const float*)d_in[0];
    const int*   actions  = (const int*)d_in[1];
    const float* mem_keys = (const float*)d_in[2];
    const float* mem_vals = (const float*)d_in[3];
    const float* w1 = (const float*)d_in[4];
    const float* b1 = (const float*)d_in[5];
    const float* w2 = (const float*)d_in[6];
    const float* b2 = (const float*)d_in[7];
    const float* w3 = (const float*)d_in[8];
    const float* b3 = (const float*)d_in[9];
    float* out = (float*)d_out;

    // workspace layout (bytes; 16B-aligned blocks)
    char* W = (char*)d_ws;
    unsigned short* kb    = (unsigned short*)W;                 // 76,800,000
    unsigned short* distb = (unsigned short*)(W + 76800000);    // 12,800,000
    unsigned short* eb    = (unsigned short*)(W + 89600000);    //    262,144
    float* kn   = (float*)(W + 89862144);                       //    300,032
    float* qnb  = (float*)(W + 90162176);                       //      1,024
    float* emb  = (float*)(W + 90163200);                       //    524,288
    int*   perm = (int*)(W + 90687488);                         //     15,360
    int*   cntb = (int*)(W + 90702848);                         //        128
    int*   idxb = (int*)(W + 90702976);                         //     51,200
    float* wb   = (float*)(W + 90754176);                       //     51,200
    float* psum = (float*)(W + 90805376);                       //    802,816
    float* psq  = (float*)(W + 91608192);                       //    802,816  (end ~92.4 MB)

    prep_keys_kernel<<<dim3((NACT * NMEM + 3) / 4), dim3(256), 0, stream>>>(mem_keys, kb, kn, NACT * NMEM);
    prep_x_kernel<<<dim3((BATCH + 3) / 4), dim3(256), 0, stream>>>(x, eb, qnb, BATCH);
    predict_kernel<<<dim3(BATCH), dim3(256), 0, stream>>>(x, w1, b1, w2, b2, w3, b3, out, 0);
    group_all_kernel<<<dim3(NSTEPS), dim3(256), 0, stream>>>(actions, perm, cntb);

    const float* cur = x;
    for (int j = 0; j < NSTEPS; ++j) {
        dist_kernel<<<dim3(NACT, NYT), dim3(256), 0, stream>>>(
            eb, kb, kn, perm + j * NACT * BATCH, cntb + j * 4, distb, psum, psq);
        select_kernel<<<dim3(BATCH), dim3(1024), 0, stream>>>(
            distb, cur, mem_keys, kn, qnb, psum, psq, actions, j, idxb, wb);
        gp_kernel<<<dim3(BATCH), dim3(512), 0, stream>>>(
            mem_vals, idxb, wb, actions, j, emb, eb, qnb, w1, b1, w2, b2, w3, b3, out);
        cur = emb;
    }
}

// Round 13
// 572.881 us; speedup vs baseline: 1.7058x; 1.0732x over previous
//
#include <hip/hip_runtime.h>

#define BATCH 256
#define DIM 512
#define NACT 3
#define NMEM 25000
#define KNB 50
#define H1N 256
#define H2N 128
#define NSTEPS 5
#define KDELTA 0.001f

#define TB 128
#define TN 64
#define BK 64
#define NCH (DIM / BK)               // 8 k-chunks
#define NYT ((NMEM + TN - 1) / TN)   // 391 n-tiles

#define CAP 2048           // candidate buffer cap

typedef __attribute__((ext_vector_type(8))) short short8;
typedef __attribute__((ext_vector_type(4))) float f32x4;

__device__ __forceinline__ unsigned short bf16rn(float f) {
    unsigned u = __float_as_uint(f);
    u += 0x7FFFu + ((u >> 16) & 1u);
    return (unsigned short)(u >> 16);
}
__device__ __forceinline__ float blo(unsigned u) { return __uint_as_float(u << 16); }
__device__ __forceinline__ float bhi(unsigned u) { return __uint_as_float(u & 0xFFFF0000u); }

// ---------- prep keys: f32 -> bf16 copy + row norms (one wave per row) ----------
__global__ __launch_bounds__(256)
void prep_keys_kernel(const float* __restrict__ rows, unsigned short* __restrict__ kb,
                      float* __restrict__ kn, int nrows) {
    int wave = threadIdx.x >> 6, lane = threadIdx.x & 63;
    int r = blockIdx.x * 4 + wave;
    if (r >= nrows) return;
    const float* p = rows + (size_t)r * DIM;
    float4 v0 = *(const float4*)(p + lane * 8);
    float4 v1 = *(const float4*)(p + lane * 8 + 4);
    float f[8] = {v0.x, v0.y, v0.z, v0.w, v1.x, v1.y, v1.z, v1.w};
    short8 hv;
    float s = 0.f;
    #pragma unroll
    for (int i = 0; i < 8; ++i) { hv[i] = (short)bf16rn(f[i]); s += f[i] * f[i]; }
    *(short8*)(kb + (size_t)r * DIM + lane * 8) = hv;
    for (int off = 32; off; off >>= 1) s += __shfl_down(s, off);
    if (lane == 0) kn[r] = s;
}

// ---------- group batch rows by action, all steps in one launch ----------
__global__ __launch_bounds__(256)
void group_all_kernel(const int* __restrict__ actions,
                      int* __restrict__ perm, int* __restrict__ cnt) {
    int step = blockIdx.x;
    __shared__ int lcnt[NACT];
    __shared__ int lperm[NACT * BATCH];
    int tid = threadIdx.x;
    if (tid < NACT) lcnt[tid] = 0;
    __syncthreads();
    int a = actions[tid * NSTEPS + step];
    int pos = atomicAdd(&lcnt[a], 1);
    lperm[a * BATCH + pos] = tid;
    __syncthreads();
    if (tid < NACT) cnt[step * 4 + tid] = lcnt[tid];
    for (int aa = 0; aa < NACT; ++aa) {
        int c = lcnt[aa];
        int f = (c > 0) ? lperm[aa * BATCH] : 0;
        for (int i = c + tid; i < BATCH; i += 256) lperm[aa * BATCH + i] = f;
    }
    __syncthreads();
    for (int i = tid; i < NACT * BATCH; i += 256)
        perm[step * NACT * BATCH + i] = lperm[i];
}

// ---------- step-0: prep x (bf16 + qn) fused with first MLP ----------
__global__ __launch_bounds__(256)
void prep_predict_kernel(const float* __restrict__ x, unsigned short* __restrict__ eb,
                         float* __restrict__ qn,
                         const float* __restrict__ w1, const float* __restrict__ b1,
                         const float* __restrict__ w2, const float* __restrict__ b2,
                         const float* __restrict__ w3, const float* __restrict__ b3,
                         float* __restrict__ out) {
    int b = blockIdx.x, tid = threadIdx.x;
    __shared__ float xs[DIM];
    __shared__ float red[256];
    __shared__ float h1[H1N];
    __shared__ float h2[H2N];
    float e0 = x[(size_t)b * DIM + tid];
    float e1 = x[(size_t)b * DIM + tid + 256];
    xs[tid] = e0; xs[tid + 256] = e1;
    eb[(size_t)b * DIM + tid] = bf16rn(e0);
    eb[(size_t)b * DIM + tid + 256] = bf16rn(e1);
    red[tid] = e0 * e0 + e1 * e1;
    __syncthreads();
    for (int s = 128; s > 0; s >>= 1) { if (tid < s) red[tid] += red[tid + s]; __syncthreads(); }
    if (tid == 0) qn[b] = red[0];
    float acc = b1[tid];
    #pragma unroll 8
    for (int d = 0; d < DIM; ++d) acc = fmaf(xs[d], w1[d * H1N + tid], acc);
    h1[tid] = acc > 0.f ? acc : expm1f(acc);
    __syncthreads();
    if (tid < H2N) {
        float a2 = b2[tid];
        #pragma unroll 8
        for (int d = 0; d < H1N; ++d) a2 = fmaf(h1[d], w2[d * H2N + tid], a2);
        h2[tid] = a2 > 0.f ? a2 : expm1f(a2);
    }
    __syncthreads();
    if (tid < 5) {
        float p = b3[tid];
        for (int d = 0; d < H2N; ++d) p = fmaf(h2[d], w3[d * 5 + tid], p);
        float o = p;
        if (tid == 1) o = 1.0f / (1.0f + expf(-p));
        out[b * (6 * 5) + tid] = o;
    }
}

// ---------- approx distance GEMM: bf16 MFMA, 2-deep reg prefetch, padded-frag skip ----------
__global__ __launch_bounds__(256)
void dist_kernel(const unsigned short* __restrict__ eb, const unsigned short* __restrict__ kb,
                 const float* __restrict__ kn, const int* __restrict__ perm,
                 const int* __restrict__ cnt, unsigned short* __restrict__ dist,
                 float* __restrict__ psum, float* __restrict__ psq) {
    int a = blockIdx.x;
    int c = cnt[a];
    int n0 = blockIdx.y * TN;

    __shared__ __align__(16) unsigned short Qh[2][TB][BK];
    __shared__ __align__(16) unsigned short Kh[2][TN][BK];
    __shared__ int rows[TB];

    int tid = threadIdx.x;
    int lane = tid & 63, wave = tid >> 6;
    int wm = wave >> 1, wn = wave & 1;

    const int qr = tid >> 1, qc = (tid & 1) * 32, qswz = (qr & 7) * 8;
    const int kr = tid >> 2, kc = (tid & 3) * 16, kswz = (kr & 7) * 8;
    int krow = (n0 + kr < NMEM) ? (n0 + kr) : (NMEM - 1);
    const unsigned short* ksrc = kb + ((size_t)a * NMEM + krow) * DIM + kc;

    int nn[2]; float knv[2]; bool nvalid[2];
    #pragma unroll
    for (int nf = 0; nf < 2; ++nf) {
        nn[nf] = n0 + wn * 32 + nf * 16 + (lane & 15);
        nvalid[nf] = nn[nf] < NMEM;
        knv[nf] = nvalid[nf] ? kn[a * NMEM + nn[nf]] : 0.f;
    }
    int slot = (blockIdx.y * 2 + wn) * BATCH;

    for (int tb0 = 0; tb0 < c; tb0 += TB) {
        __syncthreads();
        if (tid < TB) {
            int i = tb0 + tid;
            rows[tid] = perm[a * BATCH + (i < c ? i : 0)];
        }
        __syncthreads();

        const int mlim = c - tb0;   // rows >= mlim are duplicates of row 0: skip whole frags
        const unsigned short* qsrc = eb + (size_t)rows[qr] * DIM + qc;
        f32x4 acc[4][2] = {};
        short8 qA[4], qB[4], kA[2], kB[2];

        #pragma unroll
        for (int j = 0; j < 4; ++j) qA[j] = *(const short8*)(qsrc + j * 8);
        kA[0] = *(const short8*)(ksrc);
        kA[1] = *(const short8*)(ksrc + 8);
        #pragma unroll
        for (int j = 0; j < 4; ++j) qB[j] = *(const short8*)(qsrc + BK + j * 8);
        kB[0] = *(const short8*)(ksrc + BK);
        kB[1] = *(const short8*)(ksrc + BK + 8);
        #pragma unroll
        for (int j = 0; j < 4; ++j) *(short8*)&Qh[0][qr][(qc + j * 8) ^ qswz] = qA[j];
        *(short8*)&Kh[0][kr][(kc + 0) ^ kswz] = kA[0];
        *(short8*)&Kh[0][kr][(kc + 8) ^ kswz] = kA[1];
        __syncthreads();

        auto mfma_phase = [&](int B) {
            #pragma unroll
            for (int kk = 0; kk < BK; kk += 32) {
                int kcol = kk + (lane >> 4) * 8;
                short8 av[4], bv[2];
                #pragma unroll
                for (int nf = 0; nf < 2; ++nf) {
                    int n = wn * 32 + nf * 16 + (lane & 15);
                    bv[nf] = *(const short8*)&Kh[B][n][kcol ^ ((n & 7) * 8)];
                }
                #pragma unroll
                for (int mf = 0; mf < 4; ++mf) {
                    if (wm * 64 + mf * 16 < mlim) {
                        int m = wm * 64 + mf * 16 + (lane & 15);
                        av[mf] = *(const short8*)&Qh[B][m][kcol ^ ((m & 7) * 8)];
                        #pragma unroll
                        for (int nf = 0; nf < 2; ++nf)
                            acc[mf][nf] = __builtin_amdgcn_mfma_f32_16x16x32_bf16(av[mf], bv[nf], acc[mf][nf], 0, 0, 0);
                    }
                }
            }
        };

        #pragma unroll
        for (int p = 0; p < NCH / 2; ++p) {
            const int it = 2 * p;
            if (it + 2 < NCH) {
                const int d0 = (it + 2) * BK;
                #pragma unroll
                for (int j = 0; j < 4; ++j) qA[j] = *(const short8*)(qsrc + d0 + j * 8);
                kA[0] = *(const short8*)(ksrc + d0);
                kA[1] = *(const short8*)(ksrc + d0 + 8);
            }
            mfma_phase(0);
            {
                #pragma unroll
                for (int j = 0; j < 4; ++j) *(short8*)&Qh[1][qr][(qc + j * 8) ^ qswz] = qB[j];
                *(short8*)&Kh[1][kr][(kc + 0) ^ kswz] = kB[0];
                *(short8*)&Kh[1][kr][(kc + 8) ^ kswz] = kB[1];
                __syncthreads();
            }
            if (it + 3 < NCH) {
                const int d0 = (it + 3) * BK;
                #pragma unroll
                for (int j = 0; j < 4; ++j) qB[j] = *(const short8*)(qsrc + d0 + j * 8);
                kB[0] = *(const short8*)(ksrc + d0);
                kB[1] = *(const short8*)(ksrc + d0 + 8);
            }
            mfma_phase(1);
            if (it + 2 < NCH) {
                #pragma unroll
                for (int j = 0; j < 4; ++j) *(short8*)&Qh[0][qr][(qc + j * 8) ^ qswz] = qA[j];
                *(short8*)&Kh[0][kr][(kc + 0) ^ kswz] = kA[0];
                *(short8*)&Kh[0][kr][(kc + 8) ^ kswz] = kA[1];
                __syncthreads();
            }
        }

        // ---- epilogue: store bf16 dist + per-row stats partials ----
        #pragma unroll
        for (int mf = 0; mf < 4; ++mf) {
            if (wm * 64 + mf * 16 >= mlim) continue;   // padded frag: covered by real row's frag
            #pragma unroll
            for (int r = 0; r < 4; ++r) {
                int m = wm * 64 + mf * 16 + (lane >> 4) * 4 + r;
                int b = rows[m];
                float s = 0.f, q2 = 0.f;
                #pragma unroll
                for (int nf = 0; nf < 2; ++nf) {
                    if (nvalid[nf]) {
                        float d = knv[nf] - 2.0f * acc[mf][nf][r];
                        dist[(size_t)b * NMEM + nn[nf]] = bf16rn(d);
                        s += d; q2 += d * d;
                    }
                }
                #pragma unroll
                for (int x = 1; x < 16; x <<= 1) { s += __shfl_xor(s, x); q2 += __shfl_xor(q2, x); }
                if ((lane & 15) == 0) { psum[slot + b] = s; psq[slot + b] = q2; }
            }
        }
    }
}

// ---------- fused: stats -> collect -> exact refine -> top-50 -> gather -> qn -> MLP ----------
__global__ __launch_bounds__(1024)
void selgp_kernel(const unsigned short* __restrict__ dist, const float* __restrict__ emb,
                  const float* __restrict__ keys, const float* __restrict__ kn,
                  const float* __restrict__ qn,
                  const float* __restrict__ psum, const float* __restrict__ psq,
                  const int* __restrict__ actions, int step,
                  const float* __restrict__ vals,
                  float* __restrict__ emb_out, unsigned short* __restrict__ eb_out,
                  float* __restrict__ qn_out,
                  const float* __restrict__ w1, const float* __restrict__ b1,
                  const float* __restrict__ w2, const float* __restrict__ b2,
                  const float* __restrict__ w3, const float* __restrict__ b3,
                  float* __restrict__ out) {
    __shared__ float qs[DIM];          // q row (refine), later reused as new-emb xs
    __shared__ float wsum16[16], wsq16[16];
    __shared__ float Tsh, sdsh;
    __shared__ unsigned cntS;
    __shared__ int candb[CAP];
    __shared__ float dex[CAP];
    __shared__ float wsel[KNB];
    __shared__ int   isel[KNB];
    __shared__ float wsumS;
    __shared__ float part[1024];
    __shared__ float red[512];
    __shared__ float h1[H1N];
    __shared__ float h2[H2N];

    int b = blockIdx.x, tid = threadIdx.x;
    int lane = tid & 63, wid = tid >> 6;
    const uint4* d8 = (const uint4*)(dist + (size_t)b * NMEM);
    int a = actions[b * NSTEPS + step];

    if (tid < 128) *(float4*)&qs[tid * 4] = *(const float4*)(emb + (size_t)b * DIM + tid * 4);

    // ---- stats ----
    {
        float s = 0.f, q = 0.f;
        for (int i = tid; i < NYT * 2; i += 1024) {
            s += psum[i * BATCH + b];
            q += psq[i * BATCH + b];
        }
        #pragma unroll
        for (int m = 32; m; m >>= 1) { s += __shfl_xor(s, m); q += __shfl_xor(q, m); }
        if (lane == 0) { wsum16[wid] = s; wsq16[wid] = q; }
    }
    __syncthreads();
    if (tid == 0) {
        float S = 0.f, Q = 0.f;
        for (int i = 0; i < 16; ++i) { S += wsum16[i]; Q += wsq16[i]; }
        float mean = S / (float)NMEM;
        float var = Q / (float)NMEM - mean * mean;
        float sd = sqrtf(fmaxf(var, 0.f));
        sdsh = sd;
        Tsh = mean - 2.40f * sd;
    }
    __syncthreads();

    // ---- collect candidates ----
    float T = Tsh, sd = sdsh;
    for (int it = 0; it < 8; ++it) {
        if (tid == 0) cntS = 0;
        __syncthreads();
        for (int i = tid; i < NMEM / 8; i += 1024) {
            uint4 v = d8[i];
            int n = i * 8;
            float f[8] = {blo(v.x), bhi(v.x), blo(v.y), bhi(v.y),
                          blo(v.z), bhi(v.z), blo(v.w), bhi(v.w)};
            #pragma unroll
            for (int k = 0; k < 8; ++k)
                if (f[k] < T) { unsigned p = atomicAdd(&cntS, 1u); if (p < CAP) candb[p] = n + k; }
        }
        __syncthreads();
        if (cntS >= 128) break;
        T += 0.6f * sd;
        __syncthreads();
    }
    int C = (int)cntS; if (C > CAP) C = CAP;

    // ---- exact f32 refine (8 threads/cand, interleaved dims) ----
    float qnb = qn[b];
    const float* keysA = keys + (size_t)a * NMEM * DIM;
    {
        int cslot = tid >> 3, sub = tid & 7;
        int sweeps = (C + 127) >> 7;
        for (int sw = 0; sw < sweeps; ++sw) {
            int ci = sw * 128 + cslot;
            float dot = 0.f;
            int n = 0;
            if (ci < C) {
                n = candb[ci];
                const float* kr = keysA + (size_t)n * DIM;
                #pragma unroll
                for (int k = 0; k < 16; ++k) {
                    int o = sub * 4 + k * 32;
                    float4 kv = *(const float4*)(kr + o);
                    dot = fmaf(kv.x, qs[o+0], dot);
                    dot = fmaf(kv.y, qs[o+1], dot);
                    dot = fmaf(kv.z, qs[o+2], dot);
                    dot = fmaf(kv.w, qs[o+3], dot);
                }
            }
            dot += __shfl_xor(dot, 1);
            dot += __shfl_xor(dot, 2);
            dot += __shfl_xor(dot, 4);
            if (ci < C && sub == 0)
                dex[ci] = qnb + kn[a * NMEM + n] - 2.0f * dot;
        }
    }
    __syncthreads();

    // ---- exact (d, idx) rank -> top-50 in LDS ----
    for (int ci = tid; ci < C; ci += 1024) {
        float di = dex[ci]; int ni = candb[ci];
        int rank = 0;
        for (int j = 0; j < C; ++j) {
            float dj = dex[j];
            rank += (dj < di || (dj == di && candb[j] < ni)) ? 1 : 0;
        }
        if (rank < KNB) { wsel[rank] = 1.0f / (di + KDELTA); isel[rank] = ni; }
    }
    __syncthreads();
    if (tid == 0) {
        float ssum = 0.f;
        for (int i = 0; i < KNB; ++i) ssum += wsel[i];
        wsumS = ssum;
    }
    __syncthreads();
    if (tid < KNB) wsel[tid] = wsel[tid] / wsumS;
    __syncthreads();

    // ---- gather: 2 threads per dim, 25 k-terms each ----
    {
        int dim = tid & 511, h = tid >> 9;
        const float* va = vals + (size_t)a * NMEM * DIM + dim;
        float acc = 0.f;
        int k0 = h * 25;
        #pragma unroll 5
        for (int k = 0; k < 25; ++k)
            acc = fmaf(wsel[k0 + k], va[(size_t)isel[k0 + k] * DIM], acc);
        part[tid] = acc;
    }
    __syncthreads();
    if (tid < 512) {
        float e = part[tid] + part[tid + 512];
        emb_out[b * DIM + tid] = e;
        eb_out[b * DIM + tid] = bf16rn(e);
        qs[tid] = e;               // reuse qs as xs
        red[tid] = e * e;
    }
    __syncthreads();
    for (int s = 256; s > 0; s >>= 1) { if (tid < s) red[tid] += red[tid + s]; __syncthreads(); }
    if (tid == 0) qn_out[b] = red[0];
    // ---- MLP layer 1: 256 outputs, 4-way split-K ----
    {
        int o = tid & (H1N - 1), q4 = tid >> 8;
        const float* wc = w1 + (size_t)q4 * 128 * H1N + o;
        const float* xc = qs + q4 * 128;
        float s = 0.f;
        #pragma unroll 8
        for (int d = 0; d < 128; ++d) s = fmaf(xc[d], wc[(size_t)d * H1N], s);
        part[tid] = s;
    }
    __syncthreads();
    if (tid < H1N) {
        float v = part[tid] + part[tid + H1N] + part[tid + 2 * H1N] + part[tid + 3 * H1N] + b1[tid];
        h1[tid] = v > 0.f ? v : expm1f(v);
    }
    __syncthreads();
    // ---- MLP layer 2: 128 outputs, 8-way split-K ----
    {
        int o = tid & (H2N - 1), q8 = tid >> 7;
        const float* wc = w2 + (size_t)q8 * 32 * H2N + o;
        const float* hc = h1 + q8 * 32;
        float s = 0.f;
        #pragma unroll 8
        for (int d = 0; d < 32; ++d) s = fmaf(hc[d], wc[(size_t)d * H2N], s);
        part[tid] = s;
    }
    __syncthreads();
    if (tid < H2N) {
        float v = b2[tid];
        #pragma unroll
        for (int q8 = 0; q8 < 8; ++q8) v += part[tid + q8 * H2N];
        h2[tid] = v > 0.f ? v : expm1f(v);
    }
    __syncthreads();
    if (tid < 5) {
        float p = b3[tid];
        for (int d = 0; d < H2N; ++d) p = fmaf(h2[d], w3[d * 5 + tid], p);
        float o = p;
        if (tid == 1) o = 1.0f / (1.0f + expf(-p));
        out[b * (6 * 5) + (step + 1) * 5 + tid] = o;
    }
}

extern "C" void kernel_launch(void* const* d_in, const int* in_sizes, int n_in,
                              void* d_out, int out_size, void* d_ws, size_t ws_size,
                              hipStream_t stream) {
    const float* x        = (const float*)d_in[0];
    const int*   actions  = (const int*)d_in[1];
    const float* mem_keys = (const float*)d_in[2];
    const float* mem_vals = (const float*)d_in[3];
    const float* w1 = (const float*)d_in[4];
    const float* b1 = (const float*)d_in[5];
    const float* w2 = (const float*)d_in[6];
    const float* b2 = (const float*)d_in[7];
    const float* w3 = (const float*)d_in[8];
    const float* b3 = (const float*)d_in[9];
    float* out = (float*)d_out;

    // workspace layout (bytes; 16B-aligned blocks)
    char* W = (char*)d_ws;
    unsigned short* kb    = (unsigned short*)W;                 // 76,800,000
    unsigned short* distb = (unsigned short*)(W + 76800000);    // 12,800,000
    unsigned short* eb    = (unsigned short*)(W + 89600000);    //    262,144
    float* kn   = (float*)(W + 89862144);                       //    300,032
    float* qnb  = (float*)(W + 90162176);                       //      1,024
    float* emb  = (float*)(W + 90163200);                       //    524,288
    int*   perm = (int*)(W + 90687488);                         //     15,360
    int*   cntb = (int*)(W + 90702848);                         //        128
    float* psum = (float*)(W + 90702976);                       //    802,816
    float* psq  = (float*)(W + 91505792);                       //    802,816  (end ~92.3 MB)

    prep_keys_kernel<<<dim3((NACT * NMEM + 3) / 4), dim3(256), 0, stream>>>(mem_keys, kb, kn, NACT * NMEM);
    group_all_kernel<<<dim3(NSTEPS), dim3(256), 0, stream>>>(actions, perm, cntb);
    prep_predict_kernel<<<dim3(BATCH), dim3(256), 0, stream>>>(
        x, eb, qnb, w1, b1, w2, b2, w3, b3, out);

    const float* cur = x;
    for (int j = 0; j < NSTEPS; ++j) {
        dist_kernel<<<dim3(NACT, NYT), dim3(256), 0, stream>>>(
            eb, kb, kn, perm + j * NACT * BATCH, cntb + j * 4, distb, psum, psq);
        selgp_kernel<<<dim3(BATCH), dim3(1024), 0, stream>>>(
            distb, cur, mem_keys, kn, qnb, psum, psq, actions, j, mem_vals,
            emb, eb, qnb, w1, b1, w2, b2, w3, b3, out);
        cur = emb;
    }
}